// Round 8
// baseline (395.532 us; speedup 1.0000x reference)
//
#include <hip/hip_runtime.h>
#include <hip/hip_bf16.h>
#include <math.h>

typedef __attribute__((ext_vector_type(8))) short bf16x8;
typedef __attribute__((ext_vector_type(4))) float f32x4;

#define B_    4
#define C_    512
#define HW_   84
#define HP_   86      // conv output spatial (84 + 2*2 - 3 + 1)
#define XP_   88      // zero-padded input spatial
#define NPIX  (HP_*HP_)   // 7396
#define XPIX  (XP_*XP_)   // 7744
#define YSEG  ((size_t)2048 * NPIX)   // elements per partial buffer

struct Taps { float fu[12]; float fd[12]; };

__device__ __forceinline__ unsigned short f2bf(float f) {
    unsigned int u = __float_as_uint(f);
    unsigned int r = (u + 0x7fffu + ((u >> 16) & 1u)) >> 16;   // RNE
    return (unsigned short)r;
}
__device__ __forceinline__ float bf2f(unsigned short u) {
    return __uint_as_float((unsigned int)u << 16);
}

// ---------- k_prep: blocks 0..511 -> affine s; 512..1023 -> weight norm/repack ----------
__global__ __launch_bounds__(256) void k_prep(const float* __restrict__ wlat,
                                              const float* __restrict__ aff_w,
                                              const float* __restrict__ aff_b,
                                              const float* __restrict__ conv_w,
                                              float* __restrict__ s_raw,
                                              float* __restrict__ parts,
                                              unsigned short* __restrict__ wn3,
                                              float* __restrict__ w2) {
    __shared__ float red[256];
    int tid = threadIdx.x;
    if (blockIdx.x < 512) {
        int wv = tid >> 6, lane = tid & 63;
        int w = blockIdx.x * 4 + wv;            // 0..2047
        int b = w >> 9, c = w & 511;
        const float4* aw = (const float4*)(aff_w + (size_t)c * 512);
        const float4* wl = (const float4*)(wlat + b * 512);
        float4 a0 = aw[lane * 2], a1 = aw[lane * 2 + 1];
        float4 w0 = wl[lane * 2], w1 = wl[lane * 2 + 1];
        float acc = a0.x * w0.x + a0.y * w0.y + a0.z * w0.z + a0.w * w0.w
                  + a1.x * w1.x + a1.y * w1.y + a1.z * w1.z + a1.w * w1.w;
        #pragma unroll
        for (int m = 1; m < 64; m <<= 1) acc += __shfl_xor(acc, m, 64);
        if (lane == 0) {
            float s = acc * 0.04419417382415922f + aff_b[c];
            s_raw[w] = s; red[wv] = s * s;
        }
        __syncthreads();
        if (tid == 0) parts[blockIdx.x] = red[0] + red[1] + red[2] + red[3];
    } else {
        int o = blockIdx.x - 512;
        const float* wo = conv_w + (size_t)o * 4608;
        float ss = 0.f;
        for (int i = tid; i < 4608; i += 256) { float v = wo[i]; ss += v * v; }
        red[tid] = ss; __syncthreads();
        for (int off = 128; off > 0; off >>= 1) {
            if (tid < off) red[tid] += red[tid + off];
            __syncthreads();
        }
        float scale = rsqrtf(red[0] / 4608.f);
        int og = o >> 5, o32 = o & 31;
        for (int c = tid; c < 512; c += 256) {
            float s2 = 0.f;
            #pragma unroll
            for (int k = 0; k < 9; k++) { float v = wo[c * 9 + k] * scale; s2 += v * v; }
            w2[(size_t)o * 512 + c] = s2;
        }
        // coalesced wn3 writes: per-o slice is 16 runs of 288 contiguous elements
        for (int idx = tid; idx < 4608; idx += 256) {
            int cc = idx / 288, rem = idx - cc * 288;
            int kk = rem >> 5, c32 = rem & 31;
            float v = wo[(cc * 32 + c32) * 9 + kk] * scale;
            wn3[(((size_t)cc * 16 + og) * 32 + o32) * 288 + rem] = f2bf(v);
        }
    }
}

// ---------- k_dcoef3: wave-per-(b,o): reduce parts -> inv; dcoef + sn write ----------
__global__ __launch_bounds__(256) void k_dcoef3(const float* __restrict__ s_raw,
                                                const float* __restrict__ parts,
                                                const float* __restrict__ w2,
                                                float* __restrict__ sn,
                                                float* __restrict__ dcoef) {
    int wv = threadIdx.x >> 6, lane = threadIdx.x & 63;
    int w = blockIdx.x * 4 + wv;
    int b = w >> 9, o = w & 511;
    const float4* pp = (const float4*)parts;
    float4 p0 = pp[lane * 2], p1 = pp[lane * 2 + 1];
    float tot = p0.x + p0.y + p0.z + p0.w + p1.x + p1.y + p1.z + p1.w;
    #pragma unroll
    for (int m = 1; m < 64; m <<= 1) tot += __shfl_xor(tot, m, 64);
    float inv = rsqrtf(tot / 2048.f);
    const float4* sr = (const float4*)(s_raw + b * 512);
    const float4* wr = (const float4*)(w2 + (size_t)o * 512);
    float acc = 0.f;
    #pragma unroll
    for (int q = 0; q < 2; q++) {
        float4 s = sr[lane * 2 + q], ww = wr[lane * 2 + q];
        float s0 = s.x * inv, s1 = s.y * inv, s2 = s.z * inv, s3 = s.w * inv;
        acc += ww.x * s0 * s0 + ww.y * s1 * s1 + ww.z * s2 * s2 + ww.w * s3 * s3;
    }
    #pragma unroll
    for (int m = 1; m < 64; m <<= 1) acc += __shfl_xor(acc, m, 64);
    if (lane == 0) {
        dcoef[w] = rsqrtf(acc + 1e-8f);
        sn[w] = s_raw[w] * inv;
    }
}

// ---------- k_premod2: xpad2[b][cg][88*88][8ch] = bf16(x*sn), zero border ----------
__global__ __launch_bounds__(256) void k_premod2(const float* __restrict__ x,
                                                 const float* __restrict__ sn,
                                                 unsigned short* __restrict__ xpad2) {
    int cg = blockIdx.x >> 1, half = blockIdx.x & 1, b = blockIdx.y;
    float sv[8];
    #pragma unroll
    for (int e = 0; e < 8; e++) sv[e] = sn[b * 512 + cg * 8 + e];
    const float* xbase = x + ((size_t)(b * 512 + cg * 8)) * (HW_ * HW_);
    unsigned short* op = xpad2 + ((size_t)(b * 64 + cg)) * XPIX * 8;
    int p0 = half * (XPIX / 2), p1 = p0 + XPIX / 2;
    for (int pix = p0 + threadIdx.x; pix < p1; pix += 256) {
        int r = pix / XP_, cc = pix % XP_;
        unsigned int d[4] = {0u, 0u, 0u, 0u};
        if (r >= 2 && r < 86 && cc >= 2 && cc < 86) {
            int off = (r - 2) * HW_ + (cc - 2);
            #pragma unroll
            for (int e = 0; e < 4; e++) {
                unsigned short lo = f2bf(xbase[(size_t)(2 * e) * (HW_ * HW_) + off] * sv[2 * e]);
                unsigned short hi = f2bf(xbase[(size_t)(2 * e + 1) * (HW_ * HW_) + off] * sv[2 * e + 1]);
                d[e] = (unsigned int)lo | ((unsigned int)hi << 16);
            }
        }
        uint4 v; v.x = d[0]; v.y = d[1]; v.z = d[2]; v.w = d[3];
        *(uint4*)(op + (size_t)pix * 8) = v;
    }
}

// ---------- k_conv7: nt-split -> acc 32 AGPR, full ILP, 4 waves/SIMD ----------
// 2112 blocks (xcd-swizzled), 256 thr = 4 waves. Block: 8x16 pixel tile x 128 outs x half-K.
// Outer nt loop (no unroll): per-pass regs ~62 VGPR + 32 AGPR < 128 -> 4 waves/SIMD.
__global__ __launch_bounds__(256, 4) void k_conv7(const unsigned short* __restrict__ xpad2,
                                                  const unsigned short* __restrict__ wn3,
                                                  const float* __restrict__ dcoef,
                                                  const float* __restrict__ conv_b,
                                                  unsigned short* __restrict__ ypart) {
    int bid = blockIdx.x;
    int wg = (bid & 7) * 264 + (bid >> 3);
    int tile = wg % 66; int rest = wg / 66;       // rest = b*8 + seg*4 + ot
    int ot = rest & 3; int seg = (rest >> 2) & 1; int b = rest >> 3;

    int tid = threadIdx.x;
    int wv = tid >> 6, lane = tid & 63;
    int kgrp = lane >> 4, ln15 = lane & 15;
    int tr = tile / 6, tc = tile % 6;
    int r0 = tr * 8; if (r0 > 78) r0 = 78;
    int c0p = tc * 16; if (c0p > 70) c0p = 70;
    int og = ot * 4 + wv;

    const unsigned short* fb0 = xpad2 + ((size_t)(b * 64 + seg * 32 + kgrp) * XPIX + r0 * XP_ + c0p + ln15) * 8;
    unsigned short* yb = ypart + (size_t)seg * YSEG + ((size_t)b * 512) * NPIX;
    int pcol = c0p + ln15;

    #pragma unroll 1
    for (int nt = 0; nt < 2; ++nt) {
        const unsigned short* fb = fb0;
        const unsigned short* wb = wn3 + (size_t)(seg * 8) * 147456
                                 + ((size_t)(og * 32 + nt * 16 + ln15)) * 288 + kgrp * 8;
        f32x4 acc[8];
        #pragma unroll
        for (int g = 0; g < 8; g++) acc[g] = (f32x4){0.f, 0.f, 0.f, 0.f};

        #pragma unroll 1
        for (int cc = 0; cc < 8; ++cc) {
            #pragma unroll
            for (int kw = 0; kw < 3; ++kw) {
                bf16x8 F[10];
                #pragma unroll
                for (int r = 0; r < 10; ++r)
                    F[r] = *(const bf16x8*)(fb + (r * XP_ + kw) * 8);
                #pragma unroll
                for (int kh = 0; kh < 3; ++kh) {
                    int kk = kh * 3 + kw;
                    bf16x8 W = *(const bf16x8*)(wb + kk * 32);
                    #pragma unroll
                    for (int g = 0; g < 8; ++g)
                        acc[g] = __builtin_amdgcn_mfma_f32_16x16x32_bf16(W, F[g + kh], acc[g], 0, 0, 0);
                }
            }
            fb += (size_t)4 * XPIX * 8;
            wb += 147456;
        }

        // epilogue for this nt half
        #pragma unroll
        for (int r = 0; r < 4; r++) {
            int o = og * 32 + nt * 16 + kgrp * 4 + r;
            float dc = dcoef[b * 512 + o];
            float bb = seg ? conv_b[o] : 0.f;
            unsigned short* yo = yb + (size_t)o * NPIX + pcol;
            #pragma unroll
            for (int g = 0; g < 8; ++g)
                yo[(r0 + g) * HP_] = f2bf(acc[g][r] * dc + bb);
        }
    }
}

// ---------- k_resample2: full-width 28x84 strip; LDS buffers aliased; upF bf16 ----------
__global__ __launch_bounds__(512) void k_resample2(const unsigned short* __restrict__ ypart,
                                                   float* __restrict__ out, Taps taps) {
    __shared__ __align__(16) char smem[23760 + 25344];
    float (*yt)[96]           = (float(*)[96])smem;            // [38][94 used]
    unsigned short (*upF)[180] = (unsigned short(*)[180])smem; // [66][178 used]
    float (*upR)[96]          = (float(*)[96])(smem + 23760);  // [66][94 used]
    float (*dv)[180]          = (float(*)[180])(smem + 23760); // [28][178 used]

    int tid = threadIdx.x;
    int ts = blockIdx.x; int o = blockIdx.y; int b = blockIdx.z;
    int tr = ts * 28;
    const unsigned short* y0b = ypart + ((size_t)(b * 512 + o)) * NPIX;
    const unsigned short* y1b = y0b + YSEG;

    for (int idx = tid; idx < 38 * 94; idx += 512) {
        int rr = idx / 94, cc = idx % 94;
        int gr = tr - 4 + rr, gc = cc - 4;
        float v = 0.f;
        if (gr >= 0 && gr < HP_ && gc >= 0 && gc < HP_) {
            int p = gr * HP_ + gc;
            v = bf2f(y0b[p]) + bf2f(y1b[p]);
        }
        yt[rr][cc] = v;
    }
    __syncthreads();
    for (int idx = tid; idx < 33 * 94; idx += 512) {
        int q = idx / 94, cc = idx % 94;
        float aE = 0.f, aO = 0.f;
        #pragma unroll
        for (int u = 0; u < 6; u++) {
            float v = yt[q + u][cc];
            aE += taps.fu[2 * u + 1] * v;
            aO += taps.fu[2 * u] * v;
        }
        upR[2 * q][cc] = aE; upR[2 * q + 1][cc] = aO;
    }
    __syncthreads();
    for (int idx = tid; idx < 66 * 89; idx += 512) {
        int jr = idx / 89, q = idx % 89;
        float aE = 0.f, aO = 0.f;
        #pragma unroll
        for (int u = 0; u < 6; u++) {
            float v = upR[jr][q + u];
            aE += taps.fu[2 * u + 1] * v;
            aO += taps.fu[2 * u] * v;
        }
        aE = (aE < 0.f ? aE * 0.2f : aE) * 1.4142135623730951f;
        aO = (aO < 0.f ? aO * 0.2f : aO) * 1.4142135623730951f;
        aE = fminf(fmaxf(aE, -256.f), 256.f);
        aO = fminf(fmaxf(aO, -256.f), 256.f);
        unsigned int pk = (unsigned int)f2bf(aE) | ((unsigned int)f2bf(aO) << 16);
        *(unsigned int*)&upF[jr][2 * q] = pk;
    }
    __syncthreads();
    for (int idx = tid; idx < 28 * 178; idx += 512) {
        int ii = idx / 178, jc = idx % 178;
        float a = 0.f;
        #pragma unroll
        for (int t = 0; t < 12; t++) a += taps.fd[t] * bf2f(upF[2 * ii + t][jc]);
        dv[ii][jc] = a;
    }
    __syncthreads();
    for (int idx = tid; idx < 28 * 84; idx += 512) {
        int ii = idx / 84, jo = idx % 84;
        float a = 0.f;
        #pragma unroll
        for (int t = 0; t < 12; t++) a += taps.fd[t] * dv[ii][2 * jo + t];
        out[((size_t)(b * 512 + o) * 84 + (tr + ii)) * 84 + jo] = a;
    }
}

// ---------- host: Kaiser lowpass design in double ----------
static double bessel_i0(double x) {
    double s = 1.0, t = 1.0;
    for (int k = 1; k < 60; k++) {
        double u = x / (2.0 * k);
        t *= u * u;
        s += t;
        if (t < 1e-18 * s) break;
    }
    return s;
}

static void design_taps(float* h12) {
    const int N = 12;
    const double cutoff = 16.0, width = 16.0, fs = 128.0;
    double nyq = 0.5 * fs;
    double atten = 2.285 * (N - 1) * M_PI * (width / nyq) + 7.95;
    double beta;
    if (atten > 50.0) beta = 0.1102 * (atten - 8.7);
    else if (atten > 21.0) beta = 0.5842 * pow(atten - 21.0, 0.4) + 0.07886 * (atten - 21.0);
    else beta = 0.0;
    double c = cutoff / nyq;
    double h[12]; double sum = 0.0;
    double ib = bessel_i0(beta);
    for (int n = 0; n < N; n++) {
        double m = n - (N - 1) / 2.0;
        double xx = c * m;
        double sinc = (xx == 0.0) ? 1.0 : sin(M_PI * xx) / (M_PI * xx);
        double t = 2.0 * n / (N - 1) - 1.0;
        double arg = 1.0 - t * t; if (arg < 0.0) arg = 0.0;
        double w = bessel_i0(beta * sqrt(arg)) / ib;
        h[n] = c * sinc * w;
        sum += h[n];
    }
    for (int n = 0; n < N; n++) h12[n] = (float)(h[n] / sum);
}

extern "C" void kernel_launch(void* const* d_in, const int* in_sizes, int n_in,
                              void* d_out, int out_size, void* d_ws, size_t ws_size,
                              hipStream_t stream) {
    const float* x      = (const float*)d_in[0];
    const float* wlat   = (const float*)d_in[1];
    const float* aff_w  = (const float*)d_in[2];
    const float* aff_b  = (const float*)d_in[3];
    const float* conv_w = (const float*)d_in[4];
    const float* conv_b = (const float*)d_in[5];
    float* out = (float*)d_out;

    // ws layout: sn 8K | dcoef 8K | w2 1M | wn3 4.5M | xpad2 31.7M | ypart 60.6M (~98 MiB)
    char* ws = (char*)d_ws;
    float* sn    = (float*)ws;
    float* dcoef = sn + 2048;
    float* w2    = dcoef + 2048;
    unsigned short* wn3   = (unsigned short*)(w2 + 512 * 512);
    unsigned short* xpad2 = wn3 + (size_t)9 * 512 * 512;
    unsigned short* ypart = xpad2 + (size_t)B_ * 64 * XPIX * 8;
    // s_raw/parts alias ypart (consumed by k_dcoef3 before k_conv7 writes)
    float* s_raw = (float*)ypart;
    float* parts = s_raw + 2048;

    Taps taps;
    float h[12];
    design_taps(h);
    for (int t = 0; t < 12; t++) {
        taps.fu[t] = 2.0f * h[11 - t];   // (FU*UP)[::-1]
        taps.fd[t] = h[11 - t];          // FD[::-1]
    }

    k_prep   <<<dim3(1024), dim3(256), 0, stream>>>(wlat, aff_w, aff_b, conv_w, s_raw, parts, wn3, w2);
    k_dcoef3 <<<dim3(512), dim3(256), 0, stream>>>(s_raw, parts, w2, sn, dcoef);
    k_premod2<<<dim3(128, 4), dim3(256), 0, stream>>>(x, sn, xpad2);
    k_conv7  <<<dim3(2112), dim3(256), 0, stream>>>(xpad2, wn3, dcoef, conv_b, ypart);
    k_resample2<<<dim3(3, 512, 4), dim3(512), 0, stream>>>(ypart, out, taps);
}

// Round 9
// 286.153 us; speedup vs baseline: 1.3822x; 1.3822x over previous
//
#include <hip/hip_runtime.h>
#include <hip/hip_bf16.h>
#include <math.h>

typedef __attribute__((ext_vector_type(8))) short bf16x8;
typedef __attribute__((ext_vector_type(4))) float f32x4;

#define B_    4
#define C_    512
#define HW_   84
#define HP_   86      // conv output spatial (84 + 2*2 - 3 + 1)
#define XP_   88      // zero-padded input spatial
#define NPIX  (HP_*HP_)   // 7396
#define XPIX  (XP_*XP_)   // 7744
#define YSEG  ((size_t)2048 * NPIX)   // elements per partial buffer

struct Taps { float fu[12]; float fd[12]; };

__device__ __forceinline__ unsigned short f2bf(float f) {
    unsigned int u = __float_as_uint(f);
    unsigned int r = (u + 0x7fffu + ((u >> 16) & 1u)) >> 16;   // RNE
    return (unsigned short)r;
}
__device__ __forceinline__ float bf2f(unsigned short u) {
    return __uint_as_float((unsigned int)u << 16);
}
__device__ __forceinline__ void gload_lds16(const unsigned short* g, unsigned short* l) {
    __builtin_amdgcn_global_load_lds((const __attribute__((address_space(1))) void*)g,
                                     (__attribute__((address_space(3))) void*)l, 16, 0, 0);
}

// ---------- k_prep: blocks 0..511 -> affine s; 512..1023 -> weight norm/repack ----------
__global__ __launch_bounds__(256) void k_prep(const float* __restrict__ wlat,
                                              const float* __restrict__ aff_w,
                                              const float* __restrict__ aff_b,
                                              const float* __restrict__ conv_w,
                                              float* __restrict__ s_raw,
                                              float* __restrict__ parts,
                                              unsigned short* __restrict__ wn3,
                                              float* __restrict__ w2) {
    __shared__ float red[256];
    int tid = threadIdx.x;
    if (blockIdx.x < 512) {
        int wv = tid >> 6, lane = tid & 63;
        int w = blockIdx.x * 4 + wv;            // 0..2047
        int b = w >> 9, c = w & 511;
        const float4* aw = (const float4*)(aff_w + (size_t)c * 512);
        const float4* wl = (const float4*)(wlat + b * 512);
        float4 a0 = aw[lane * 2], a1 = aw[lane * 2 + 1];
        float4 w0 = wl[lane * 2], w1 = wl[lane * 2 + 1];
        float acc = a0.x * w0.x + a0.y * w0.y + a0.z * w0.z + a0.w * w0.w
                  + a1.x * w1.x + a1.y * w1.y + a1.z * w1.z + a1.w * w1.w;
        #pragma unroll
        for (int m = 1; m < 64; m <<= 1) acc += __shfl_xor(acc, m, 64);
        if (lane == 0) {
            float s = acc * 0.04419417382415922f + aff_b[c];
            s_raw[w] = s; red[wv] = s * s;
        }
        __syncthreads();
        if (tid == 0) parts[blockIdx.x] = red[0] + red[1] + red[2] + red[3];
    } else {
        int o = blockIdx.x - 512;
        const float* wo = conv_w + (size_t)o * 4608;
        float ss = 0.f;
        for (int i = tid; i < 4608; i += 256) { float v = wo[i]; ss += v * v; }
        red[tid] = ss; __syncthreads();
        for (int off = 128; off > 0; off >>= 1) {
            if (tid < off) red[tid] += red[tid + off];
            __syncthreads();
        }
        float scale = rsqrtf(red[0] / 4608.f);
        int og = o >> 5, o32 = o & 31;
        for (int c = tid; c < 512; c += 256) {
            float s2 = 0.f;
            #pragma unroll
            for (int k = 0; k < 9; k++) { float v = wo[c * 9 + k] * scale; s2 += v * v; }
            w2[(size_t)o * 512 + c] = s2;
        }
        // coalesced wn3 writes: per-o slice is 16 runs of 288 contiguous elements
        for (int idx = tid; idx < 4608; idx += 256) {
            int cc = idx / 288, rem = idx - cc * 288;
            int kk = rem >> 5, c32 = rem & 31;
            float v = wo[(cc * 32 + c32) * 9 + kk] * scale;
            wn3[(((size_t)cc * 16 + og) * 32 + o32) * 288 + rem] = f2bf(v);
        }
    }
}

// ---------- k_dcoef3: wave-per-(b,o): reduce parts -> inv; dcoef + sn write ----------
__global__ __launch_bounds__(256) void k_dcoef3(const float* __restrict__ s_raw,
                                                const float* __restrict__ parts,
                                                const float* __restrict__ w2,
                                                float* __restrict__ sn,
                                                float* __restrict__ dcoef) {
    int wv = threadIdx.x >> 6, lane = threadIdx.x & 63;
    int w = blockIdx.x * 4 + wv;
    int b = w >> 9, o = w & 511;
    const float4* pp = (const float4*)parts;
    float4 p0 = pp[lane * 2], p1 = pp[lane * 2 + 1];
    float tot = p0.x + p0.y + p0.z + p0.w + p1.x + p1.y + p1.z + p1.w;
    #pragma unroll
    for (int m = 1; m < 64; m <<= 1) tot += __shfl_xor(tot, m, 64);
    float inv = rsqrtf(tot / 2048.f);
    const float4* sr = (const float4*)(s_raw + b * 512);
    const float4* wr = (const float4*)(w2 + (size_t)o * 512);
    float acc = 0.f;
    #pragma unroll
    for (int q = 0; q < 2; q++) {
        float4 s = sr[lane * 2 + q], ww = wr[lane * 2 + q];
        float s0 = s.x * inv, s1 = s.y * inv, s2 = s.z * inv, s3 = s.w * inv;
        acc += ww.x * s0 * s0 + ww.y * s1 * s1 + ww.z * s2 * s2 + ww.w * s3 * s3;
    }
    #pragma unroll
    for (int m = 1; m < 64; m <<= 1) acc += __shfl_xor(acc, m, 64);
    if (lane == 0) {
        dcoef[w] = rsqrtf(acc + 1e-8f);
        sn[w] = s_raw[w] * inv;
    }
}

// ---------- k_premod2: xpad2[b][cg][88*88][8ch] = bf16(x*sn), zero border ----------
__global__ __launch_bounds__(256) void k_premod2(const float* __restrict__ x,
                                                 const float* __restrict__ sn,
                                                 unsigned short* __restrict__ xpad2) {
    int cg = blockIdx.x >> 1, half = blockIdx.x & 1, b = blockIdx.y;
    float sv[8];
    #pragma unroll
    for (int e = 0; e < 8; e++) sv[e] = sn[b * 512 + cg * 8 + e];
    const float* xbase = x + ((size_t)(b * 512 + cg * 8)) * (HW_ * HW_);
    unsigned short* op = xpad2 + ((size_t)(b * 64 + cg)) * XPIX * 8;
    int p0 = half * (XPIX / 2), p1 = p0 + XPIX / 2;
    for (int pix = p0 + threadIdx.x; pix < p1; pix += 256) {
        int r = pix / XP_, cc = pix % XP_;
        unsigned int d[4] = {0u, 0u, 0u, 0u};
        if (r >= 2 && r < 86 && cc >= 2 && cc < 86) {
            int off = (r - 2) * HW_ + (cc - 2);
            #pragma unroll
            for (int e = 0; e < 4; e++) {
                unsigned short lo = f2bf(xbase[(size_t)(2 * e) * (HW_ * HW_) + off] * sv[2 * e]);
                unsigned short hi = f2bf(xbase[(size_t)(2 * e + 1) * (HW_ * HW_) + off] * sv[2 * e + 1]);
                d[e] = (unsigned int)lo | ((unsigned int)hi << 16);
            }
        }
        uint4 v; v.x = d[0]; v.y = d[1]; v.z = d[2]; v.w = d[3];
        *(uint4*)(op + (size_t)pix * 8) = v;
    }
}

// ---------- k_conv8: 2-phase LDS-staged implicit GEMM (F via LDS, W via L1) ----------
// 2112 blocks (xcd-swizzled), 256 thr = 4 waves. Block: 8x16 pixel tile x 128 outs x half-K.
// LDS: 2 bufs x [4 kgrp][192 pix][8 ch] (24.6 KB). Wave wv stages kgrp=wv via 3x global_load_lds.
__global__ __launch_bounds__(256, 3) void k_conv8(const unsigned short* __restrict__ xpad2,
                                                  const unsigned short* __restrict__ wn3,
                                                  const float* __restrict__ dcoef,
                                                  const float* __restrict__ conv_b,
                                                  unsigned short* __restrict__ ypart) {
    __shared__ __align__(16) unsigned short xs[2][4][192][8];

    int bid = blockIdx.x;
    int wg = (bid & 7) * 264 + (bid >> 3);
    int tile = wg % 66; int rest = wg / 66;       // rest = b*8 + seg*4 + ot
    int ot = rest & 3; int seg = (rest >> 2) & 1; int b = rest >> 3;

    int tid = threadIdx.x;
    int wv = tid >> 6, lane = tid & 63;
    int kgrp = lane >> 4, ln15 = lane & 15;
    int tr = tile / 6, tc = tile % 6;
    int r0 = tr * 8; if (r0 > 78) r0 = 78;
    int c0p = tc * 16; if (c0p > 70) c0p = 70;
    int og = ot * 4 + wv;

    // per-lane staging source pointers (wave wv stages channel-group wv of each chunk)
    const unsigned short* xseg = xpad2 + ((size_t)(b * 64 + seg * 32 + wv)) * XPIX * 8;
    int pA = lane, pB = 64 + lane, pC = (128 + lane > 179) ? 179 : 128 + lane;
    const unsigned short* gA = xseg + ((size_t)((r0 + pA / 18) * XP_ + c0p + pA % 18)) * 8;
    const unsigned short* gB = xseg + ((size_t)((r0 + pB / 18) * XP_ + c0p + pB % 18)) * 8;
    const unsigned short* gC = xseg + ((size_t)((r0 + pC / 18) * XP_ + c0p + pC % 18)) * 8;
    const size_t cstride = (size_t)4 * XPIX * 8;

    const unsigned short* wb0 = wn3 + (size_t)(seg * 8) * 147456 + ((size_t)(og * 32 + ln15)) * 288 + kgrp * 8;
    const unsigned short* wb1 = wb0 + (size_t)16 * 288;

    f32x4 acc[8][2];
    #pragma unroll
    for (int g = 0; g < 8; g++) { acc[g][0] = (f32x4){0,0,0,0}; acc[g][1] = (f32x4){0,0,0,0}; }

    // prologue: stage chunk 0 into buf 0
    gload_lds16(gA, &xs[0][wv][0][0]);
    gload_lds16(gB, &xs[0][wv][64][0]);
    gload_lds16(gC, &xs[0][wv][128][0]);
    gA += cstride; gB += cstride; gC += cstride;
    __syncthreads();                              // drains vmcnt -> buf0 ready

    #pragma unroll 1
    for (int cc = 0; cc < 8; ++cc) {
        int cur = cc & 1;
        if (cc < 7) {                             // issue next-chunk staging first (hides latency)
            int nb = cur ^ 1;
            gload_lds16(gA, &xs[nb][wv][0][0]);
            gload_lds16(gB, &xs[nb][wv][64][0]);
            gload_lds16(gC, &xs[nb][wv][128][0]);
            gA += cstride; gB += cstride; gC += cstride;
        }
        #pragma unroll
        for (int kw = 0; kw < 3; ++kw) {
            bf16x8 F[10];
            #pragma unroll
            for (int r = 0; r < 10; ++r)
                F[r] = *(const bf16x8*)&xs[cur][kgrp][r * 18 + ln15 + kw][0];
            #pragma unroll
            for (int kh = 0; kh < 3; ++kh) {
                int kk = kh * 3 + kw;
                bf16x8 W0 = *(const bf16x8*)(wb0 + kk * 32);
                bf16x8 W1 = *(const bf16x8*)(wb1 + kk * 32);
                #pragma unroll
                for (int g = 0; g < 8; ++g) {
                    acc[g][0] = __builtin_amdgcn_mfma_f32_16x16x32_bf16(W0, F[g + kh], acc[g][0], 0, 0, 0);
                    acc[g][1] = __builtin_amdgcn_mfma_f32_16x16x32_bf16(W1, F[g + kh], acc[g][1], 0, 0, 0);
                }
            }
        }
        wb0 += 147456; wb1 += 147456;
        __syncthreads();                          // staging done + all reads of xs[cur] done
    }

    float dcv[2][4], bvs[2][4];
    #pragma unroll
    for (int nt = 0; nt < 2; nt++)
        #pragma unroll
        for (int r = 0; r < 4; r++) {
            int o = og * 32 + nt * 16 + kgrp * 4 + r;
            dcv[nt][r] = dcoef[b * 512 + o];
            bvs[nt][r] = seg ? conv_b[o] : 0.f;
        }
    unsigned short* yp = ypart + (size_t)seg * YSEG;
    int pcol = c0p + ln15;
    #pragma unroll
    for (int g = 0; g < 8; ++g) {
        int prow = r0 + g;
        #pragma unroll
        for (int nt = 0; nt < 2; nt++)
            #pragma unroll
            for (int r = 0; r < 4; r++) {
                int o = og * 32 + nt * 16 + kgrp * 4 + r;
                yp[((size_t)(b * 512 + o)) * NPIX + prow * HP_ + pcol] =
                    f2bf(acc[g][nt][r] * dcv[nt][r] + bvs[nt][r]);
            }
    }
}

// ---------- k_resample2: full-width 28x84 strip; LDS buffers aliased; upF bf16 ----------
__global__ __launch_bounds__(512) void k_resample2(const unsigned short* __restrict__ ypart,
                                                   float* __restrict__ out, Taps taps) {
    __shared__ __align__(16) char smem[23760 + 25344];
    float (*yt)[96]           = (float(*)[96])smem;            // [38][94 used]
    unsigned short (*upF)[180] = (unsigned short(*)[180])smem; // [66][178 used]
    float (*upR)[96]          = (float(*)[96])(smem + 23760);  // [66][94 used]
    float (*dv)[180]          = (float(*)[180])(smem + 23760); // [28][178 used]

    int tid = threadIdx.x;
    int ts = blockIdx.x; int o = blockIdx.y; int b = blockIdx.z;
    int tr = ts * 28;
    const unsigned short* y0b = ypart + ((size_t)(b * 512 + o)) * NPIX;
    const unsigned short* y1b = y0b + YSEG;

    for (int idx = tid; idx < 38 * 94; idx += 512) {
        int rr = idx / 94, cc = idx % 94;
        int gr = tr - 4 + rr, gc = cc - 4;
        float v = 0.f;
        if (gr >= 0 && gr < HP_ && gc >= 0 && gc < HP_) {
            int p = gr * HP_ + gc;
            v = bf2f(y0b[p]) + bf2f(y1b[p]);
        }
        yt[rr][cc] = v;
    }
    __syncthreads();
    for (int idx = tid; idx < 33 * 94; idx += 512) {
        int q = idx / 94, cc = idx % 94;
        float aE = 0.f, aO = 0.f;
        #pragma unroll
        for (int u = 0; u < 6; u++) {
            float v = yt[q + u][cc];
            aE += taps.fu[2 * u + 1] * v;
            aO += taps.fu[2 * u] * v;
        }
        upR[2 * q][cc] = aE; upR[2 * q + 1][cc] = aO;
    }
    __syncthreads();
    for (int idx = tid; idx < 66 * 89; idx += 512) {
        int jr = idx / 89, q = idx % 89;
        float aE = 0.f, aO = 0.f;
        #pragma unroll
        for (int u = 0; u < 6; u++) {
            float v = upR[jr][q + u];
            aE += taps.fu[2 * u + 1] * v;
            aO += taps.fu[2 * u] * v;
        }
        aE = (aE < 0.f ? aE * 0.2f : aE) * 1.4142135623730951f;
        aO = (aO < 0.f ? aO * 0.2f : aO) * 1.4142135623730951f;
        aE = fminf(fmaxf(aE, -256.f), 256.f);
        aO = fminf(fmaxf(aO, -256.f), 256.f);
        unsigned int pk = (unsigned int)f2bf(aE) | ((unsigned int)f2bf(aO) << 16);
        *(unsigned int*)&upF[jr][2 * q] = pk;
    }
    __syncthreads();
    for (int idx = tid; idx < 28 * 178; idx += 512) {
        int ii = idx / 178, jc = idx % 178;
        float a = 0.f;
        #pragma unroll
        for (int t = 0; t < 12; t++) a += taps.fd[t] * bf2f(upF[2 * ii + t][jc]);
        dv[ii][jc] = a;
    }
    __syncthreads();
    for (int idx = tid; idx < 28 * 84; idx += 512) {
        int ii = idx / 84, jo = idx % 84;
        float a = 0.f;
        #pragma unroll
        for (int t = 0; t < 12; t++) a += taps.fd[t] * dv[ii][2 * jo + t];
        out[((size_t)(b * 512 + o) * 84 + (tr + ii)) * 84 + jo] = a;
    }
}

// ---------- host: Kaiser lowpass design in double ----------
static double bessel_i0(double x) {
    double s = 1.0, t = 1.0;
    for (int k = 1; k < 60; k++) {
        double u = x / (2.0 * k);
        t *= u * u;
        s += t;
        if (t < 1e-18 * s) break;
    }
    return s;
}

static void design_taps(float* h12) {
    const int N = 12;
    const double cutoff = 16.0, width = 16.0, fs = 128.0;
    double nyq = 0.5 * fs;
    double atten = 2.285 * (N - 1) * M_PI * (width / nyq) + 7.95;
    double beta;
    if (atten > 50.0) beta = 0.1102 * (atten - 8.7);
    else if (atten > 21.0) beta = 0.5842 * pow(atten - 21.0, 0.4) + 0.07886 * (atten - 21.0);
    else beta = 0.0;
    double c = cutoff / nyq;
    double h[12]; double sum = 0.0;
    double ib = bessel_i0(beta);
    for (int n = 0; n < N; n++) {
        double m = n - (N - 1) / 2.0;
        double xx = c * m;
        double sinc = (xx == 0.0) ? 1.0 : sin(M_PI * xx) / (M_PI * xx);
        double t = 2.0 * n / (N - 1) - 1.0;
        double arg = 1.0 - t * t; if (arg < 0.0) arg = 0.0;
        double w = bessel_i0(beta * sqrt(arg)) / ib;
        h[n] = c * sinc * w;
        sum += h[n];
    }
    for (int n = 0; n < N; n++) h12[n] = (float)(h[n] / sum);
}

extern "C" void kernel_launch(void* const* d_in, const int* in_sizes, int n_in,
                              void* d_out, int out_size, void* d_ws, size_t ws_size,
                              hipStream_t stream) {
    const float* x      = (const float*)d_in[0];
    const float* wlat   = (const float*)d_in[1];
    const float* aff_w  = (const float*)d_in[2];
    const float* aff_b  = (const float*)d_in[3];
    const float* conv_w = (const float*)d_in[4];
    const float* conv_b = (const float*)d_in[5];
    float* out = (float*)d_out;

    // ws layout: sn 8K | dcoef 8K | w2 1M | wn3 4.5M | xpad2 31.7M | ypart 60.6M (~98 MiB)
    char* ws = (char*)d_ws;
    float* sn    = (float*)ws;
    float* dcoef = sn + 2048;
    float* w2    = dcoef + 2048;
    unsigned short* wn3   = (unsigned short*)(w2 + 512 * 512);
    unsigned short* xpad2 = wn3 + (size_t)9 * 512 * 512;
    unsigned short* ypart = xpad2 + (size_t)B_ * 64 * XPIX * 8;
    // s_raw/parts alias ypart (consumed by k_dcoef3 before k_conv8 writes)
    float* s_raw = (float*)ypart;
    float* parts = s_raw + 2048;

    Taps taps;
    float h[12];
    design_taps(h);
    for (int t = 0; t < 12; t++) {
        taps.fu[t] = 2.0f * h[11 - t];   // (FU*UP)[::-1]
        taps.fd[t] = h[11 - t];          // FD[::-1]
    }

    k_prep   <<<dim3(1024), dim3(256), 0, stream>>>(wlat, aff_w, aff_b, conv_w, s_raw, parts, wn3, w2);
    k_dcoef3 <<<dim3(512), dim3(256), 0, stream>>>(s_raw, parts, w2, sn, dcoef);
    k_premod2<<<dim3(128, 4), dim3(256), 0, stream>>>(x, sn, xpad2);
    k_conv8  <<<dim3(2112), dim3(256), 0, stream>>>(xpad2, wn3, dcoef, conv_b, ypart);
    k_resample2<<<dim3(3, 512, 4), dim3(512), 0, stream>>>(ypart, out, taps);
}

// Round 10
// 272.535 us; speedup vs baseline: 1.4513x; 1.0500x over previous
//
#include <hip/hip_runtime.h>
#include <hip/hip_bf16.h>
#include <math.h>

typedef __attribute__((ext_vector_type(8))) short bf16x8;
typedef __attribute__((ext_vector_type(4))) float f32x4;

#define B_    4
#define C_    512
#define HW_   84
#define HP_   86      // conv output spatial (84 + 2*2 - 3 + 1)
#define XP_   88      // zero-padded input spatial
#define NPIX  (HP_*HP_)   // 7396
#define XPIX  (XP_*XP_)   // 7744
#define YSEG  ((size_t)2048 * NPIX)   // elements per partial buffer

struct Taps { float fu[12]; float fd[12]; };

__device__ __forceinline__ unsigned short f2bf(float f) {
    unsigned int u = __float_as_uint(f);
    unsigned int r = (u + 0x7fffu + ((u >> 16) & 1u)) >> 16;   // RNE
    return (unsigned short)r;
}
__device__ __forceinline__ float bf2f(unsigned short u) {
    return __uint_as_float((unsigned int)u << 16);
}
__device__ __forceinline__ void gload_lds16(const unsigned short* g, unsigned short* l) {
    __builtin_amdgcn_global_load_lds((const __attribute__((address_space(1))) void*)g,
                                     (__attribute__((address_space(3))) void*)l, 16, 0, 0);
}

// ---------- k_prep: blocks 0..511 -> affine s; 512..1023 -> weight norm/repack ----------
__global__ __launch_bounds__(256) void k_prep(const float* __restrict__ wlat,
                                              const float* __restrict__ aff_w,
                                              const float* __restrict__ aff_b,
                                              const float* __restrict__ conv_w,
                                              float* __restrict__ s_raw,
                                              float* __restrict__ parts,
                                              unsigned short* __restrict__ wn3,
                                              float* __restrict__ w2) {
    __shared__ float red[256];
    __shared__ float wlds[4608];
    int tid = threadIdx.x;
    if (blockIdx.x < 512) {
        int wv = tid >> 6, lane = tid & 63;
        int w = blockIdx.x * 4 + wv;            // 0..2047
        int b = w >> 9, c = w & 511;
        const float4* aw = (const float4*)(aff_w + (size_t)c * 512);
        const float4* wl = (const float4*)(wlat + b * 512);
        float4 a0 = aw[lane * 2], a1 = aw[lane * 2 + 1];
        float4 w0 = wl[lane * 2], w1 = wl[lane * 2 + 1];
        float acc = a0.x * w0.x + a0.y * w0.y + a0.z * w0.z + a0.w * w0.w
                  + a1.x * w1.x + a1.y * w1.y + a1.z * w1.z + a1.w * w1.w;
        #pragma unroll
        for (int m = 1; m < 64; m <<= 1) acc += __shfl_xor(acc, m, 64);
        if (lane == 0) {
            float s = acc * 0.04419417382415922f + aff_b[c];
            s_raw[w] = s; red[wv] = s * s;
        }
        __syncthreads();
        if (tid == 0) parts[blockIdx.x] = red[0] + red[1] + red[2] + red[3];
    } else {
        int o = blockIdx.x - 512;
        const float* wo = conv_w + (size_t)o * 4608;
        float ss = 0.f;
        for (int i = tid; i < 4608; i += 256) { float v = wo[i]; wlds[i] = v; ss += v * v; }
        red[tid] = ss; __syncthreads();
        for (int off = 128; off > 0; off >>= 1) {
            if (tid < off) red[tid] += red[tid + off];
            __syncthreads();
        }
        float scale = rsqrtf(red[0] / 4608.f);
        int og = o >> 5, o32 = o & 31;
        for (int c = tid; c < 512; c += 256) {
            float s2 = 0.f;
            #pragma unroll
            for (int k = 0; k < 9; k++) { float v = wlds[c * 9 + k] * scale; s2 += v * v; }
            w2[(size_t)o * 512 + c] = s2;
        }
        // coalesced wn3 writes from LDS: per-o slice = 16 runs of 288 contiguous elems
        for (int idx = tid; idx < 4608; idx += 256) {
            int cc = idx / 288, rem = idx - cc * 288;
            int kk = rem >> 5, c32 = rem & 31;
            float v = wlds[(cc * 32 + c32) * 9 + kk] * scale;
            wn3[(((size_t)cc * 16 + og) * 32 + o32) * 288 + rem] = f2bf(v);
        }
    }
}

// ---------- k_dcoef3: wave-per-(b,o): reduce parts -> inv; dcoef + sn write ----------
__global__ __launch_bounds__(256) void k_dcoef3(const float* __restrict__ s_raw,
                                                const float* __restrict__ parts,
                                                const float* __restrict__ w2,
                                                float* __restrict__ sn,
                                                float* __restrict__ dcoef) {
    int wv = threadIdx.x >> 6, lane = threadIdx.x & 63;
    int w = blockIdx.x * 4 + wv;
    int b = w >> 9, o = w & 511;
    const float4* pp = (const float4*)parts;
    float4 p0 = pp[lane * 2], p1 = pp[lane * 2 + 1];
    float tot = p0.x + p0.y + p0.z + p0.w + p1.x + p1.y + p1.z + p1.w;
    #pragma unroll
    for (int m = 1; m < 64; m <<= 1) tot += __shfl_xor(tot, m, 64);
    float inv = rsqrtf(tot / 2048.f);
    const float4* sr = (const float4*)(s_raw + b * 512);
    const float4* wr = (const float4*)(w2 + (size_t)o * 512);
    float acc = 0.f;
    #pragma unroll
    for (int q = 0; q < 2; q++) {
        float4 s = sr[lane * 2 + q], ww = wr[lane * 2 + q];
        float s0 = s.x * inv, s1 = s.y * inv, s2 = s.z * inv, s3 = s.w * inv;
        acc += ww.x * s0 * s0 + ww.y * s1 * s1 + ww.z * s2 * s2 + ww.w * s3 * s3;
    }
    #pragma unroll
    for (int m = 1; m < 64; m <<= 1) acc += __shfl_xor(acc, m, 64);
    if (lane == 0) {
        dcoef[w] = rsqrtf(acc + 1e-8f);
        sn[w] = s_raw[w] * inv;
    }
}

// ---------- k_premod2: xpad2[b][cg][88*88][8ch] = bf16(x*sn), zero border ----------
__global__ __launch_bounds__(256) void k_premod2(const float* __restrict__ x,
                                                 const float* __restrict__ sn,
                                                 unsigned short* __restrict__ xpad2) {
    int cg = blockIdx.x >> 1, half = blockIdx.x & 1, b = blockIdx.y;
    float sv[8];
    #pragma unroll
    for (int e = 0; e < 8; e++) sv[e] = sn[b * 512 + cg * 8 + e];
    const float* xbase = x + ((size_t)(b * 512 + cg * 8)) * (HW_ * HW_);
    unsigned short* op = xpad2 + ((size_t)(b * 64 + cg)) * XPIX * 8;
    int p0 = half * (XPIX / 2), p1 = p0 + XPIX / 2;
    for (int pix = p0 + threadIdx.x; pix < p1; pix += 256) {
        int r = pix / XP_, cc = pix % XP_;
        unsigned int d[4] = {0u, 0u, 0u, 0u};
        if (r >= 2 && r < 86 && cc >= 2 && cc < 86) {
            int off = (r - 2) * HW_ + (cc - 2);
            #pragma unroll
            for (int e = 0; e < 4; e++) {
                unsigned short lo = f2bf(xbase[(size_t)(2 * e) * (HW_ * HW_) + off] * sv[2 * e]);
                unsigned short hi = f2bf(xbase[(size_t)(2 * e + 1) * (HW_ * HW_) + off] * sv[2 * e + 1]);
                d[e] = (unsigned int)lo | ((unsigned int)hi << 16);
            }
        }
        uint4 v; v.x = d[0]; v.y = d[1]; v.z = d[2]; v.w = d[3];
        *(uint4*)(op + (size_t)pix * 8) = v;
    }
}

// ---------- k_conv9: LDS-staged implicit GEMM, 2 chunks per phase (half the barriers) ----------
// 2112 blocks (xcd-swizzled), 256 thr = 4 waves. Block: 8x16 pixel tile x 128 outs x half-K.
// LDS: 2 bufs x [4 kgrp][384 pix(2 chunks)][8 ch] = 48 KB. Wave wv stages kgrp=wv, 6x gload_lds.
__global__ __launch_bounds__(256, 3) void k_conv9(const unsigned short* __restrict__ xpad2,
                                                  const unsigned short* __restrict__ wn3,
                                                  const float* __restrict__ dcoef,
                                                  const float* __restrict__ conv_b,
                                                  unsigned short* __restrict__ ypart) {
    __shared__ __align__(16) unsigned short xs[2][4][384][8];

    int bid = blockIdx.x;
    int wg = (bid & 7) * 264 + (bid >> 3);
    int tile = wg % 66; int rest = wg / 66;       // rest = b*8 + seg*4 + ot
    int ot = rest & 3; int seg = (rest >> 2) & 1; int b = rest >> 3;

    int tid = threadIdx.x;
    int wv = tid >> 6, lane = tid & 63;
    int kgrp = lane >> 4, ln15 = lane & 15;
    int tr = tile / 6, tc = tile % 6;
    int r0 = tr * 8; if (r0 > 78) r0 = 78;
    int c0p = tc * 16; if (c0p > 70) c0p = 70;
    int og = ot * 4 + wv;

    // per-lane staging source pointers (wave wv stages channel-group wv of each chunk)
    const unsigned short* xseg = xpad2 + ((size_t)(b * 64 + seg * 32 + wv)) * XPIX * 8;
    int pA = lane, pB = 64 + lane, pC = (128 + lane > 179) ? 179 : 128 + lane;
    const unsigned short* gA = xseg + ((size_t)((r0 + pA / 18) * XP_ + c0p + pA % 18)) * 8;
    const unsigned short* gB = xseg + ((size_t)((r0 + pB / 18) * XP_ + c0p + pB % 18)) * 8;
    const unsigned short* gC = xseg + ((size_t)((r0 + pC / 18) * XP_ + c0p + pC % 18)) * 8;
    const size_t cstride = (size_t)4 * XPIX * 8;

    const unsigned short* wb0 = wn3 + (size_t)(seg * 8) * 147456 + ((size_t)(og * 32 + ln15)) * 288 + kgrp * 8;
    const unsigned short* wb1 = wb0 + (size_t)16 * 288;

    f32x4 acc[8][2];
    #pragma unroll
    for (int g = 0; g < 8; g++) { acc[g][0] = (f32x4){0,0,0,0}; acc[g][1] = (f32x4){0,0,0,0}; }

    // stage a chunk-pair into buffer bf, then advance the source pointers
    auto stage2 = [&](int bf) {
        gload_lds16(gA,           &xs[bf][wv][0][0]);
        gload_lds16(gB,           &xs[bf][wv][64][0]);
        gload_lds16(gC,           &xs[bf][wv][128][0]);
        gload_lds16(gA + cstride, &xs[bf][wv][192][0]);
        gload_lds16(gB + cstride, &xs[bf][wv][256][0]);
        gload_lds16(gC + cstride, &xs[bf][wv][320][0]);
        gA += 2 * cstride; gB += 2 * cstride; gC += 2 * cstride;
    };

    stage2(0);
    __syncthreads();                              // drains vmcnt -> buf0 (chunks 0,1) ready

    #pragma unroll 1
    for (int ph = 0; ph < 4; ++ph) {
        int cur = ph & 1;
        if (ph < 3) stage2(cur ^ 1);              // issue next pair first (hides latency)
        #pragma unroll
        for (int hf = 0; hf < 2; ++hf) {
            int pbase = hf * 192;
            #pragma unroll
            for (int kw = 0; kw < 3; ++kw) {
                bf16x8 F[10];
                #pragma unroll
                for (int r = 0; r < 10; ++r)
                    F[r] = *(const bf16x8*)&xs[cur][kgrp][pbase + r * 18 + ln15 + kw][0];
                #pragma unroll
                for (int kh = 0; kh < 3; ++kh) {
                    int kk = kh * 3 + kw;
                    bf16x8 W0 = *(const bf16x8*)(wb0 + kk * 32);
                    bf16x8 W1 = *(const bf16x8*)(wb1 + kk * 32);
                    #pragma unroll
                    for (int g = 0; g < 8; ++g) {
                        acc[g][0] = __builtin_amdgcn_mfma_f32_16x16x32_bf16(W0, F[g + kh], acc[g][0], 0, 0, 0);
                        acc[g][1] = __builtin_amdgcn_mfma_f32_16x16x32_bf16(W1, F[g + kh], acc[g][1], 0, 0, 0);
                    }
                }
            }
            wb0 += 147456; wb1 += 147456;
        }
        __syncthreads();                          // staging done + all reads of xs[cur] done
    }

    float dcv[2][4], bvs[2][4];
    #pragma unroll
    for (int nt = 0; nt < 2; nt++)
        #pragma unroll
        for (int r = 0; r < 4; r++) {
            int o = og * 32 + nt * 16 + kgrp * 4 + r;
            dcv[nt][r] = dcoef[b * 512 + o];
            bvs[nt][r] = seg ? conv_b[o] : 0.f;
        }
    unsigned short* yp = ypart + (size_t)seg * YSEG;
    int pcol = c0p + ln15;
    #pragma unroll
    for (int g = 0; g < 8; ++g) {
        int prow = r0 + g;
        #pragma unroll
        for (int nt = 0; nt < 2; nt++)
            #pragma unroll
            for (int r = 0; r < 4; r++) {
                int o = og * 32 + nt * 16 + kgrp * 4 + r;
                yp[((size_t)(b * 512 + o)) * NPIX + prow * HP_ + pcol] =
                    f2bf(acc[g][nt][r] * dcv[nt][r] + bvs[nt][r]);
            }
    }
}

// ---------- k_resample3: full-width strip; stage4/5 use paired LDS reads ----------
__global__ __launch_bounds__(512) void k_resample3(const unsigned short* __restrict__ ypart,
                                                   float* __restrict__ out, Taps taps) {
    __shared__ __align__(16) char smem[23760 + 25344];
    float (*yt)[96]           = (float(*)[96])smem;            // [38][94 used]
    unsigned short (*upF)[180] = (unsigned short(*)[180])smem; // [66][178 used]
    float (*upR)[96]          = (float(*)[96])(smem + 23760);  // [66][94 used]
    float (*dv)[180]          = (float(*)[180])(smem + 23760); // [28][178 used]

    int tid = threadIdx.x;
    int ts = blockIdx.x; int o = blockIdx.y; int b = blockIdx.z;
    int tr = ts * 28;
    const unsigned short* y0b = ypart + ((size_t)(b * 512 + o)) * NPIX;
    const unsigned short* y1b = y0b + YSEG;

    for (int idx = tid; idx < 38 * 94; idx += 512) {
        int rr = idx / 94, cc = idx % 94;
        int gr = tr - 4 + rr, gc = cc - 4;
        float v = 0.f;
        if (gr >= 0 && gr < HP_ && gc >= 0 && gc < HP_) {
            int p = gr * HP_ + gc;
            v = bf2f(y0b[p]) + bf2f(y1b[p]);
        }
        yt[rr][cc] = v;
    }
    __syncthreads();
    for (int idx = tid; idx < 33 * 94; idx += 512) {
        int q = idx / 94, cc = idx % 94;
        float aE = 0.f, aO = 0.f;
        #pragma unroll
        for (int u = 0; u < 6; u++) {
            float v = yt[q + u][cc];
            aE += taps.fu[2 * u + 1] * v;
            aO += taps.fu[2 * u] * v;
        }
        upR[2 * q][cc] = aE; upR[2 * q + 1][cc] = aO;
    }
    __syncthreads();
    for (int idx = tid; idx < 66 * 89; idx += 512) {
        int jr = idx / 89, q = idx % 89;
        float aE = 0.f, aO = 0.f;
        #pragma unroll
        for (int u = 0; u < 6; u++) {
            float v = upR[jr][q + u];
            aE += taps.fu[2 * u + 1] * v;
            aO += taps.fu[2 * u] * v;
        }
        aE = (aE < 0.f ? aE * 0.2f : aE) * 1.4142135623730951f;
        aO = (aO < 0.f ? aO * 0.2f : aO) * 1.4142135623730951f;
        aE = fminf(fmaxf(aE, -256.f), 256.f);
        aO = fminf(fmaxf(aO, -256.f), 256.f);
        unsigned int pk = (unsigned int)f2bf(aE) | ((unsigned int)f2bf(aO) << 16);
        *(unsigned int*)&upF[jr][2 * q] = pk;
    }
    __syncthreads();
    // stage 4: vertical down, two columns per iteration via u32 reads of upF
    for (int idx = tid; idx < 28 * 89; idx += 512) {
        int ii = idx / 89, jp = idx % 89;
        float a0 = 0.f, a1 = 0.f;
        #pragma unroll
        for (int t = 0; t < 12; t++) {
            unsigned int pk = *(const unsigned int*)&upF[2 * ii + t][2 * jp];
            a0 += taps.fd[t] * bf2f((unsigned short)(pk & 0xffffu));
            a1 += taps.fd[t] * bf2f((unsigned short)(pk >> 16));
        }
        *(float2*)&dv[ii][2 * jp] = make_float2(a0, a1);
    }
    __syncthreads();
    // stage 5: horizontal down via float2 reads + store
    for (int idx = tid; idx < 28 * 84; idx += 512) {
        int ii = idx / 84, jo = idx % 84;
        const float2* dp = (const float2*)&dv[ii][2 * jo];
        float a = 0.f;
        #pragma unroll
        for (int t = 0; t < 6; t++) {
            float2 d = dp[t];
            a += taps.fd[2 * t] * d.x + taps.fd[2 * t + 1] * d.y;
        }
        out[((size_t)(b * 512 + o) * 84 + (tr + ii)) * 84 + jo] = a;
    }
}

// ---------- host: Kaiser lowpass design in double ----------
static double bessel_i0(double x) {
    double s = 1.0, t = 1.0;
    for (int k = 1; k < 60; k++) {
        double u = x / (2.0 * k);
        t *= u * u;
        s += t;
        if (t < 1e-18 * s) break;
    }
    return s;
}

static void design_taps(float* h12) {
    const int N = 12;
    const double cutoff = 16.0, width = 16.0, fs = 128.0;
    double nyq = 0.5 * fs;
    double atten = 2.285 * (N - 1) * M_PI * (width / nyq) + 7.95;
    double beta;
    if (atten > 50.0) beta = 0.1102 * (atten - 8.7);
    else if (atten > 21.0) beta = 0.5842 * pow(atten - 21.0, 0.4) + 0.07886 * (atten - 21.0);
    else beta = 0.0;
    double c = cutoff / nyq;
    double h[12]; double sum = 0.0;
    double ib = bessel_i0(beta);
    for (int n = 0; n < N; n++) {
        double m = n - (N - 1) / 2.0;
        double xx = c * m;
        double sinc = (xx == 0.0) ? 1.0 : sin(M_PI * xx) / (M_PI * xx);
        double t = 2.0 * n / (N - 1) - 1.0;
        double arg = 1.0 - t * t; if (arg < 0.0) arg = 0.0;
        double w = bessel_i0(beta * sqrt(arg)) / ib;
        h[n] = c * sinc * w;
        sum += h[n];
    }
    for (int n = 0; n < N; n++) h12[n] = (float)(h[n] / sum);
}

extern "C" void kernel_launch(void* const* d_in, const int* in_sizes, int n_in,
                              void* d_out, int out_size, void* d_ws, size_t ws_size,
                              hipStream_t stream) {
    const float* x      = (const float*)d_in[0];
    const float* wlat   = (const float*)d_in[1];
    const float* aff_w  = (const float*)d_in[2];
    const float* aff_b  = (const float*)d_in[3];
    const float* conv_w = (const float*)d_in[4];
    const float* conv_b = (const float*)d_in[5];
    float* out = (float*)d_out;

    // ws layout: sn 8K | dcoef 8K | w2 1M | wn3 4.5M | xpad2 31.7M | ypart 60.6M (~98 MiB)
    char* ws = (char*)d_ws;
    float* sn    = (float*)ws;
    float* dcoef = sn + 2048;
    float* w2    = dcoef + 2048;
    unsigned short* wn3   = (unsigned short*)(w2 + 512 * 512);
    unsigned short* xpad2 = wn3 + (size_t)9 * 512 * 512;
    unsigned short* ypart = xpad2 + (size_t)B_ * 64 * XPIX * 8;
    // s_raw/parts alias ypart (consumed by k_dcoef3 before k_conv9 writes)
    float* s_raw = (float*)ypart;
    float* parts = s_raw + 2048;

    Taps taps;
    float h[12];
    design_taps(h);
    for (int t = 0; t < 12; t++) {
        taps.fu[t] = 2.0f * h[11 - t];   // (FU*UP)[::-1]
        taps.fd[t] = h[11 - t];          // FD[::-1]
    }

    k_prep   <<<dim3(1024), dim3(256), 0, stream>>>(wlat, aff_w, aff_b, conv_w, s_raw, parts, wn3, w2);
    k_dcoef3 <<<dim3(512), dim3(256), 0, stream>>>(s_raw, parts, w2, sn, dcoef);
    k_premod2<<<dim3(128, 4), dim3(256), 0, stream>>>(x, sn, xpad2);
    k_conv9  <<<dim3(2112), dim3(256), 0, stream>>>(xpad2, wn3, dcoef, conv_b, ypart);
    k_resample3<<<dim3(3, 512, 4), dim3(512), 0, stream>>>(ypart, out, taps);
}

// Round 11
// 256.144 us; speedup vs baseline: 1.5442x; 1.0640x over previous
//
#include <hip/hip_runtime.h>
#include <hip/hip_bf16.h>
#include <math.h>

typedef __attribute__((ext_vector_type(8))) short bf16x8;
typedef __attribute__((ext_vector_type(4))) float f32x4;

#define B_    4
#define C_    512
#define HW_   84
#define HP_   86      // conv output spatial (84 + 2*2 - 3 + 1)
#define XP_   88      // zero-padded input spatial
#define NPIX  (HP_*HP_)   // 7396
#define XPIX  (XP_*XP_)   // 7744
#define YSEG  ((size_t)2048 * NPIX)   // elements per partial buffer

struct Taps { float fu[12]; float fd[12]; };

__device__ __forceinline__ unsigned short f2bf(float f) {
    unsigned int u = __float_as_uint(f);
    unsigned int r = (u + 0x7fffu + ((u >> 16) & 1u)) >> 16;   // RNE
    return (unsigned short)r;
}
__device__ __forceinline__ float bf2f(unsigned short u) {
    return __uint_as_float((unsigned int)u << 16);
}
__device__ __forceinline__ void gload_lds16(const unsigned short* g, unsigned short* l) {
    __builtin_amdgcn_global_load_lds((const __attribute__((address_space(1))) void*)g,
                                     (__attribute__((address_space(3))) void*)l, 16, 0, 0);
}

// ---------- k_prep: blocks 0..511 -> affine s; 512..1023 -> weight norm/repack ----------
__global__ __launch_bounds__(256) void k_prep(const float* __restrict__ wlat,
                                              const float* __restrict__ aff_w,
                                              const float* __restrict__ aff_b,
                                              const float* __restrict__ conv_w,
                                              float* __restrict__ s_raw,
                                              float* __restrict__ parts,
                                              unsigned short* __restrict__ wn3,
                                              float* __restrict__ w2) {
    __shared__ float red[256];
    __shared__ float wlds[4608];
    int tid = threadIdx.x;
    if (blockIdx.x < 512) {
        int wv = tid >> 6, lane = tid & 63;
        int w = blockIdx.x * 4 + wv;            // 0..2047
        int b = w >> 9, c = w & 511;
        const float4* aw = (const float4*)(aff_w + (size_t)c * 512);
        const float4* wl = (const float4*)(wlat + b * 512);
        float4 a0 = aw[lane * 2], a1 = aw[lane * 2 + 1];
        float4 w0 = wl[lane * 2], w1 = wl[lane * 2 + 1];
        float acc = a0.x * w0.x + a0.y * w0.y + a0.z * w0.z + a0.w * w0.w
                  + a1.x * w1.x + a1.y * w1.y + a1.z * w1.z + a1.w * w1.w;
        #pragma unroll
        for (int m = 1; m < 64; m <<= 1) acc += __shfl_xor(acc, m, 64);
        if (lane == 0) {
            float s = acc * 0.04419417382415922f + aff_b[c];
            s_raw[w] = s; red[wv] = s * s;
        }
        __syncthreads();
        if (tid == 0) parts[blockIdx.x] = red[0] + red[1] + red[2] + red[3];
    } else {
        int o = blockIdx.x - 512;
        const float* wo = conv_w + (size_t)o * 4608;
        float ss = 0.f;
        for (int i = tid; i < 4608; i += 256) { float v = wo[i]; wlds[i] = v; ss += v * v; }
        red[tid] = ss; __syncthreads();
        for (int off = 128; off > 0; off >>= 1) {
            if (tid < off) red[tid] += red[tid + off];
            __syncthreads();
        }
        float scale = rsqrtf(red[0] / 4608.f);
        int og = o >> 5, o32 = o & 31;
        for (int c = tid; c < 512; c += 256) {
            float s2 = 0.f;
            #pragma unroll
            for (int k = 0; k < 9; k++) { float v = wlds[c * 9 + k] * scale; s2 += v * v; }
            w2[(size_t)o * 512 + c] = s2;
        }
        // coalesced wn3 writes from LDS: per-o slice = 16 runs of 288 contiguous elems
        for (int idx = tid; idx < 4608; idx += 256) {
            int cc = idx / 288, rem = idx - cc * 288;
            int kk = rem >> 5, c32 = rem & 31;
            float v = wlds[(cc * 32 + c32) * 9 + kk] * scale;
            wn3[(((size_t)cc * 16 + og) * 32 + o32) * 288 + rem] = f2bf(v);
        }
    }
}

// ---------- k_moddc: blocks 0..511 premod (self-computed inv); 512..1023 dcoef ----------
__global__ __launch_bounds__(256) void k_moddc(const float* __restrict__ s_raw,
                                               const float* __restrict__ parts,
                                               const float* __restrict__ w2,
                                               const float* __restrict__ x,
                                               float* __restrict__ dcoef,
                                               unsigned short* __restrict__ xpad2) {
    int lane = threadIdx.x & 63;
    // wave-local total of parts[0..511] -> inv (no barriers)
    const float4* pp = (const float4*)parts;
    float4 p0 = pp[lane * 2], p1 = pp[lane * 2 + 1];
    float tot = p0.x + p0.y + p0.z + p0.w + p1.x + p1.y + p1.z + p1.w;
    #pragma unroll
    for (int m = 1; m < 64; m <<= 1) tot += __shfl_xor(tot, m, 64);
    float inv = rsqrtf(tot / 2048.f);

    if (blockIdx.x >= 512) {
        // dcoef for 4 (b,o) pairs per block (one per wave)
        int wv = threadIdx.x >> 6;
        int w = (blockIdx.x - 512) * 4 + wv;
        int b = w >> 9, o = w & 511;
        const float4* sr = (const float4*)(s_raw + b * 512);
        const float4* wr = (const float4*)(w2 + (size_t)o * 512);
        float acc = 0.f;
        #pragma unroll
        for (int q = 0; q < 2; q++) {
            float4 s = sr[lane * 2 + q], ww = wr[lane * 2 + q];
            float s0 = s.x * inv, s1 = s.y * inv, s2 = s.z * inv, s3 = s.w * inv;
            acc += ww.x * s0 * s0 + ww.y * s1 * s1 + ww.z * s2 * s2 + ww.w * s3 * s3;
        }
        #pragma unroll
        for (int m = 1; m < 64; m <<= 1) acc += __shfl_xor(acc, m, 64);
        if (lane == 0) dcoef[w] = rsqrtf(acc + 1e-8f);
    } else {
        // premod: xpad2[b][cg][88*88][8ch] = bf16(x * s_raw*inv), zero border
        int pb = blockIdx.x;
        int b = pb >> 7; int rem = pb & 127;
        int cg = rem >> 1, half = rem & 1;
        float sv[8];
        #pragma unroll
        for (int e = 0; e < 8; e++) sv[e] = s_raw[b * 512 + cg * 8 + e] * inv;
        const float* xbase = x + ((size_t)(b * 512 + cg * 8)) * (HW_ * HW_);
        unsigned short* op = xpad2 + ((size_t)(b * 64 + cg)) * XPIX * 8;
        int p0i = half * (XPIX / 2), p1i = p0i + XPIX / 2;
        for (int pix = p0i + threadIdx.x; pix < p1i; pix += 256) {
            int r = pix / XP_, cc = pix % XP_;
            unsigned int d[4] = {0u, 0u, 0u, 0u};
            if (r >= 2 && r < 86 && cc >= 2 && cc < 86) {
                int off = (r - 2) * HW_ + (cc - 2);
                #pragma unroll
                for (int e = 0; e < 4; e++) {
                    unsigned short lo = f2bf(xbase[(size_t)(2 * e) * (HW_ * HW_) + off] * sv[2 * e]);
                    unsigned short hi = f2bf(xbase[(size_t)(2 * e + 1) * (HW_ * HW_) + off] * sv[2 * e + 1]);
                    d[e] = (unsigned int)lo | ((unsigned int)hi << 16);
                }
            }
            uint4 v; v.x = d[0]; v.y = d[1]; v.z = d[2]; v.w = d[3];
            *(uint4*)(op + (size_t)pix * 8) = v;
        }
    }
}

// ---------- k_conv9: LDS-staged implicit GEMM, 2 chunks per phase (frozen, 143.5us) ----------
__global__ __launch_bounds__(256, 3) void k_conv9(const unsigned short* __restrict__ xpad2,
                                                  const unsigned short* __restrict__ wn3,
                                                  const float* __restrict__ dcoef,
                                                  const float* __restrict__ conv_b,
                                                  unsigned short* __restrict__ ypart) {
    __shared__ __align__(16) unsigned short xs[2][4][384][8];

    int bid = blockIdx.x;
    int wg = (bid & 7) * 264 + (bid >> 3);
    int tile = wg % 66; int rest = wg / 66;       // rest = b*8 + seg*4 + ot
    int ot = rest & 3; int seg = (rest >> 2) & 1; int b = rest >> 3;

    int tid = threadIdx.x;
    int wv = tid >> 6, lane = tid & 63;
    int kgrp = lane >> 4, ln15 = lane & 15;
    int tr = tile / 6, tc = tile % 6;
    int r0 = tr * 8; if (r0 > 78) r0 = 78;
    int c0p = tc * 16; if (c0p > 70) c0p = 70;
    int og = ot * 4 + wv;

    const unsigned short* xseg = xpad2 + ((size_t)(b * 64 + seg * 32 + wv)) * XPIX * 8;
    int pA = lane, pB = 64 + lane, pC = (128 + lane > 179) ? 179 : 128 + lane;
    const unsigned short* gA = xseg + ((size_t)((r0 + pA / 18) * XP_ + c0p + pA % 18)) * 8;
    const unsigned short* gB = xseg + ((size_t)((r0 + pB / 18) * XP_ + c0p + pB % 18)) * 8;
    const unsigned short* gC = xseg + ((size_t)((r0 + pC / 18) * XP_ + c0p + pC % 18)) * 8;
    const size_t cstride = (size_t)4 * XPIX * 8;

    const unsigned short* wb0 = wn3 + (size_t)(seg * 8) * 147456 + ((size_t)(og * 32 + ln15)) * 288 + kgrp * 8;
    const unsigned short* wb1 = wb0 + (size_t)16 * 288;

    f32x4 acc[8][2];
    #pragma unroll
    for (int g = 0; g < 8; g++) { acc[g][0] = (f32x4){0,0,0,0}; acc[g][1] = (f32x4){0,0,0,0}; }

    auto stage2 = [&](int bf) {
        gload_lds16(gA,           &xs[bf][wv][0][0]);
        gload_lds16(gB,           &xs[bf][wv][64][0]);
        gload_lds16(gC,           &xs[bf][wv][128][0]);
        gload_lds16(gA + cstride, &xs[bf][wv][192][0]);
        gload_lds16(gB + cstride, &xs[bf][wv][256][0]);
        gload_lds16(gC + cstride, &xs[bf][wv][320][0]);
        gA += 2 * cstride; gB += 2 * cstride; gC += 2 * cstride;
    };

    stage2(0);
    __syncthreads();

    #pragma unroll 1
    for (int ph = 0; ph < 4; ++ph) {
        int cur = ph & 1;
        if (ph < 3) stage2(cur ^ 1);
        #pragma unroll
        for (int hf = 0; hf < 2; ++hf) {
            int pbase = hf * 192;
            #pragma unroll
            for (int kw = 0; kw < 3; ++kw) {
                bf16x8 F[10];
                #pragma unroll
                for (int r = 0; r < 10; ++r)
                    F[r] = *(const bf16x8*)&xs[cur][kgrp][pbase + r * 18 + ln15 + kw][0];
                #pragma unroll
                for (int kh = 0; kh < 3; ++kh) {
                    int kk = kh * 3 + kw;
                    bf16x8 W0 = *(const bf16x8*)(wb0 + kk * 32);
                    bf16x8 W1 = *(const bf16x8*)(wb1 + kk * 32);
                    #pragma unroll
                    for (int g = 0; g < 8; ++g) {
                        acc[g][0] = __builtin_amdgcn_mfma_f32_16x16x32_bf16(W0, F[g + kh], acc[g][0], 0, 0, 0);
                        acc[g][1] = __builtin_amdgcn_mfma_f32_16x16x32_bf16(W1, F[g + kh], acc[g][1], 0, 0, 0);
                    }
                }
            }
            wb0 += 147456; wb1 += 147456;
        }
        __syncthreads();
    }

    float dcv[2][4], bvs[2][4];
    #pragma unroll
    for (int nt = 0; nt < 2; nt++)
        #pragma unroll
        for (int r = 0; r < 4; r++) {
            int o = og * 32 + nt * 16 + kgrp * 4 + r;
            dcv[nt][r] = dcoef[b * 512 + o];
            bvs[nt][r] = seg ? conv_b[o] : 0.f;
        }
    unsigned short* yp = ypart + (size_t)seg * YSEG;
    int pcol = c0p + ln15;
    #pragma unroll
    for (int g = 0; g < 8; ++g) {
        int prow = r0 + g;
        #pragma unroll
        for (int nt = 0; nt < 2; nt++)
            #pragma unroll
            for (int r = 0; r < 4; r++) {
                int o = og * 32 + nt * 16 + kgrp * 4 + r;
                yp[((size_t)(b * 512 + o)) * NPIX + prow * HP_ + pcol] =
                    f2bf(acc[g][nt][r] * dcv[nt][r] + bvs[nt][r]);
            }
    }
}

// ---------- k_resample4: sliding-window register reuse in all filter stages ----------
// grid (3, 512, 4), 512 threads. LDS aliased: buf1 = yt|upF, buf2 = upR|dv.
__global__ __launch_bounds__(512) void k_resample4(const unsigned short* __restrict__ ypart,
                                                   float* __restrict__ out, Taps taps) {
    __shared__ __align__(16) char smem[23760 + 25344];
    float (*yt)[96]            = (float(*)[96])smem;            // [38][94 used]
    unsigned short (*upF)[180] = (unsigned short(*)[180])smem;  // [66][178 used]
    float (*upR)[96]           = (float(*)[96])(smem + 23760);  // [66][94 used]
    float (*dv)[180]           = (float(*)[180])(smem + 23760); // [28][178 used]

    int tid = threadIdx.x;
    int ts = blockIdx.x; int o = blockIdx.y; int b = blockIdx.z;
    int tr = ts * 28;
    const unsigned short* y0b = ypart + ((size_t)(b * 512 + o)) * NPIX;
    const unsigned short* y1b = y0b + YSEG;

    // stage 1: load y (sum of partials), rows tr-4..tr+33, cols -4..89
    for (int idx = tid; idx < 38 * 94; idx += 512) {
        int rr = idx / 94, cc = idx % 94;
        int gr = tr - 4 + rr, gc = cc - 4;
        float v = 0.f;
        if (gr >= 0 && gr < HP_ && gc >= 0 && gc < HP_) {
            int p = gr * HP_ + gc;
            v = bf2f(y0b[p]) + bf2f(y1b[p]);
        }
        yt[rr][cc] = v;
    }
    __syncthreads();
    // stage 2: vertical up; run of 3 q per thread (33 = 11x3), window 8 rows
    for (int idx = tid; idx < 11 * 94; idx += 512) {
        int ri = idx / 94, cc = idx % 94;
        int q0 = ri * 3;
        float w[8];
        #pragma unroll
        for (int u = 0; u < 8; u++) w[u] = yt[q0 + u][cc];
        #pragma unroll
        for (int j = 0; j < 3; j++) {
            float aE = 0.f, aO = 0.f;
            #pragma unroll
            for (int u = 0; u < 6; u++) {
                float v = w[j + u];
                aE += taps.fu[2 * u + 1] * v;
                aO += taps.fu[2 * u] * v;
            }
            upR[2 * (q0 + j)][cc] = aE;
            upR[2 * (q0 + j) + 1][cc] = aO;
        }
    }
    __syncthreads();
    // stage 3: horizontal up + act + clamp; run of 4 q per thread (89 = 22x4+1), window 9
    for (int idx = tid; idx < 66 * 23; idx += 512) {
        int jr = idx / 23, rq = idx % 23;
        int q0 = rq * 4;
        int n = 89 - q0; if (n > 4) n = 4;
        float w[9];
        #pragma unroll
        for (int u = 0; u < 9; u++) w[u] = (u < n + 5) ? upR[jr][q0 + u] : 0.f;
        #pragma unroll
        for (int j = 0; j < 4; j++) {
            if (j < n) {
                float aE = 0.f, aO = 0.f;
                #pragma unroll
                for (int u = 0; u < 6; u++) {
                    float v = w[j + u];
                    aE += taps.fu[2 * u + 1] * v;
                    aO += taps.fu[2 * u] * v;
                }
                aE = (aE < 0.f ? aE * 0.2f : aE) * 1.4142135623730951f;
                aO = (aO < 0.f ? aO * 0.2f : aO) * 1.4142135623730951f;
                aE = fminf(fmaxf(aE, -256.f), 256.f);
                aO = fminf(fmaxf(aO, -256.f), 256.f);
                unsigned int pk = (unsigned int)f2bf(aE) | ((unsigned int)f2bf(aO) << 16);
                *(unsigned int*)&upF[jr][2 * (q0 + j)] = pk;
            }
        }
    }
    __syncthreads();
    // stage 4: vertical down; run of 4 ii per thread (28 = 7x4), window 18 rows, col-pair jp
    for (int idx = tid; idx < 7 * 89; idx += 512) {
        int ri = idx / 89, jp = idx % 89;
        int ii0 = ri * 4;
        float lo[18], hi[18];
        #pragma unroll
        for (int t = 0; t < 18; t++) {
            unsigned int pk = *(const unsigned int*)&upF[2 * ii0 + t][2 * jp];
            lo[t] = bf2f((unsigned short)(pk & 0xffffu));
            hi[t] = bf2f((unsigned short)(pk >> 16));
        }
        #pragma unroll
        for (int j = 0; j < 4; j++) {
            float a0 = 0.f, a1 = 0.f;
            #pragma unroll
            for (int t = 0; t < 12; t++) {
                a0 += taps.fd[t] * lo[2 * j + t];
                a1 += taps.fd[t] * hi[2 * j + t];
            }
            *(float2*)&dv[ii0 + j][2 * jp] = make_float2(a0, a1);
        }
    }
    __syncthreads();
    // stage 5: horizontal down; run of 4 jo per thread (84 = 21x4), window 18, float4 store
    for (int idx = tid; idx < 28 * 21; idx += 512) {
        int ii = idx / 21, rj = idx % 21;
        int jo0 = rj * 4;
        float w[18];
        const float2* dp = (const float2*)&dv[ii][2 * jo0];
        #pragma unroll
        for (int t = 0; t < 9; t++) {
            float2 d = dp[t];
            w[2 * t] = d.x; w[2 * t + 1] = d.y;
        }
        float4 res;
        #pragma unroll
        for (int j = 0; j < 4; j++) {
            float a = 0.f;
            #pragma unroll
            for (int t = 0; t < 12; t++) a += taps.fd[t] * w[2 * j + t];
            ((float*)&res)[j] = a;
        }
        *(float4*)&out[((size_t)(b * 512 + o) * 84 + (tr + ii)) * 84 + jo0] = res;
    }
}

// ---------- host: Kaiser lowpass design in double ----------
static double bessel_i0(double x) {
    double s = 1.0, t = 1.0;
    for (int k = 1; k < 60; k++) {
        double u = x / (2.0 * k);
        t *= u * u;
        s += t;
        if (t < 1e-18 * s) break;
    }
    return s;
}

static void design_taps(float* h12) {
    const int N = 12;
    const double cutoff = 16.0, width = 16.0, fs = 128.0;
    double nyq = 0.5 * fs;
    double atten = 2.285 * (N - 1) * M_PI * (width / nyq) + 7.95;
    double beta;
    if (atten > 50.0) beta = 0.1102 * (atten - 8.7);
    else if (atten > 21.0) beta = 0.5842 * pow(atten - 21.0, 0.4) + 0.07886 * (atten - 21.0);
    else beta = 0.0;
    double c = cutoff / nyq;
    double h[12]; double sum = 0.0;
    double ib = bessel_i0(beta);
    for (int n = 0; n < N; n++) {
        double m = n - (N - 1) / 2.0;
        double xx = c * m;
        double sinc = (xx == 0.0) ? 1.0 : sin(M_PI * xx) / (M_PI * xx);
        double t = 2.0 * n / (N - 1) - 1.0;
        double arg = 1.0 - t * t; if (arg < 0.0) arg = 0.0;
        double w = bessel_i0(beta * sqrt(arg)) / ib;
        h[n] = c * sinc * w;
        sum += h[n];
    }
    for (int n = 0; n < N; n++) h12[n] = (float)(h[n] / sum);
}

extern "C" void kernel_launch(void* const* d_in, const int* in_sizes, int n_in,
                              void* d_out, int out_size, void* d_ws, size_t ws_size,
                              hipStream_t stream) {
    const float* x      = (const float*)d_in[0];
    const float* wlat   = (const float*)d_in[1];
    const float* aff_w  = (const float*)d_in[2];
    const float* aff_b  = (const float*)d_in[3];
    const float* conv_w = (const float*)d_in[4];
    const float* conv_b = (const float*)d_in[5];
    float* out = (float*)d_out;

    // ws layout: (unused 8K) | dcoef 8K | w2 1M | wn3 4.5M | xpad2 31.7M | ypart 60.6M (~98 MiB)
    char* ws = (char*)d_ws;
    float* dcoef = (float*)ws + 2048;
    float* w2    = dcoef + 2048;
    unsigned short* wn3   = (unsigned short*)(w2 + 512 * 512);
    unsigned short* xpad2 = wn3 + (size_t)9 * 512 * 512;
    unsigned short* ypart = xpad2 + (size_t)B_ * 64 * XPIX * 8;
    // s_raw/parts alias ypart (consumed by k_moddc before k_conv9 writes)
    float* s_raw = (float*)ypart;
    float* parts = s_raw + 2048;

    Taps taps;
    float h[12];
    design_taps(h);
    for (int t = 0; t < 12; t++) {
        taps.fu[t] = 2.0f * h[11 - t];   // (FU*UP)[::-1]
        taps.fd[t] = h[11 - t];          // FD[::-1]
    }

    k_prep   <<<dim3(1024), dim3(256), 0, stream>>>(wlat, aff_w, aff_b, conv_w, s_raw, parts, wn3, w2);
    k_moddc  <<<dim3(1024), dim3(256), 0, stream>>>(s_raw, parts, w2, x, dcoef, xpad2);
    k_conv9  <<<dim3(2112), dim3(256), 0, stream>>>(xpad2, wn3, dcoef, conv_b, ypart);
    k_resample4<<<dim3(3, 512, 4), dim3(512), 0, stream>>>(ypart, out, taps);
}

// Round 12
// 252.683 us; speedup vs baseline: 1.5653x; 1.0137x over previous
//
#include <hip/hip_runtime.h>
#include <hip/hip_bf16.h>
#include <math.h>

typedef __attribute__((ext_vector_type(8))) short bf16x8;
typedef __attribute__((ext_vector_type(4))) float f32x4;

#define B_    4
#define C_    512
#define HW_   84
#define HP_   86      // conv output spatial (84 + 2*2 - 3 + 1)
#define XP_   88      // zero-padded input spatial
#define NPIX  (HP_*HP_)   // 7396
#define XPIX  (XP_*XP_)   // 7744
#define YSEG  ((size_t)2048 * NPIX)   // elements per partial buffer

struct Taps { float fu[12]; float fd[12]; };

__device__ __forceinline__ unsigned short f2bf(float f) {
    unsigned int u = __float_as_uint(f);
    unsigned int r = (u + 0x7fffu + ((u >> 16) & 1u)) >> 16;   // RNE
    return (unsigned short)r;
}
__device__ __forceinline__ float bf2f(unsigned short u) {
    return __uint_as_float((unsigned int)u << 16);
}
__device__ __forceinline__ void gload_lds16(const unsigned short* g, unsigned short* l) {
    __builtin_amdgcn_global_load_lds((const __attribute__((address_space(1))) void*)g,
                                     (__attribute__((address_space(3))) void*)l, 16, 0, 0);
}

// ---------- k_prep: blocks 0..511 -> affine s; 512..1023 -> weight norm/repack ----------
__global__ __launch_bounds__(256) void k_prep(const float* __restrict__ wlat,
                                              const float* __restrict__ aff_w,
                                              const float* __restrict__ aff_b,
                                              const float* __restrict__ conv_w,
                                              float* __restrict__ s_raw,
                                              float* __restrict__ parts,
                                              unsigned short* __restrict__ wn3,
                                              float* __restrict__ w2) {
    __shared__ float red[256];
    __shared__ float wlds[4608];
    int tid = threadIdx.x;
    if (blockIdx.x < 512) {
        int wv = tid >> 6, lane = tid & 63;
        int w = blockIdx.x * 4 + wv;            // 0..2047
        int b = w >> 9, c = w & 511;
        const float4* aw = (const float4*)(aff_w + (size_t)c * 512);
        const float4* wl = (const float4*)(wlat + b * 512);
        float4 a0 = aw[lane * 2], a1 = aw[lane * 2 + 1];
        float4 w0 = wl[lane * 2], w1 = wl[lane * 2 + 1];
        float acc = a0.x * w0.x + a0.y * w0.y + a0.z * w0.z + a0.w * w0.w
                  + a1.x * w1.x + a1.y * w1.y + a1.z * w1.z + a1.w * w1.w;
        #pragma unroll
        for (int m = 1; m < 64; m <<= 1) acc += __shfl_xor(acc, m, 64);
        if (lane == 0) {
            float s = acc * 0.04419417382415922f + aff_b[c];
            s_raw[w] = s; red[wv] = s * s;
        }
        __syncthreads();
        if (tid == 0) parts[blockIdx.x] = red[0] + red[1] + red[2] + red[3];
    } else {
        int o = blockIdx.x - 512;
        const float* wo = conv_w + (size_t)o * 4608;
        float ss = 0.f;
        for (int i = tid; i < 4608; i += 256) { float v = wo[i]; wlds[i] = v; ss += v * v; }
        red[tid] = ss; __syncthreads();
        for (int off = 128; off > 0; off >>= 1) {
            if (tid < off) red[tid] += red[tid + off];
            __syncthreads();
        }
        float scale = rsqrtf(red[0] / 4608.f);
        int og = o >> 5, o32 = o & 31;
        for (int c = tid; c < 512; c += 256) {
            float s2 = 0.f;
            #pragma unroll
            for (int k = 0; k < 9; k++) { float v = wlds[c * 9 + k] * scale; s2 += v * v; }
            w2[(size_t)o * 512 + c] = s2;
        }
        for (int idx = tid; idx < 4608; idx += 256) {
            int cc = idx / 288, rem = idx - cc * 288;
            int kk = rem >> 5, c32 = rem & 31;
            float v = wlds[(cc * 32 + c32) * 9 + kk] * scale;
            wn3[(((size_t)cc * 16 + og) * 32 + o32) * 288 + rem] = f2bf(v);
        }
    }
}

// ---------- k_moddc: blocks 0..511 premod (pixel-pair float2); 512..1023 dcoef ----------
__global__ __launch_bounds__(256) void k_moddc(const float* __restrict__ s_raw,
                                               const float* __restrict__ parts,
                                               const float* __restrict__ w2,
                                               const float* __restrict__ x,
                                               float* __restrict__ dcoef,
                                               unsigned short* __restrict__ xpad2) {
    int lane = threadIdx.x & 63;
    // wave-local total of parts[0..511] -> inv (no barriers)
    const float4* pp = (const float4*)parts;
    float4 p0 = pp[lane * 2], p1 = pp[lane * 2 + 1];
    float tot = p0.x + p0.y + p0.z + p0.w + p1.x + p1.y + p1.z + p1.w;
    #pragma unroll
    for (int m = 1; m < 64; m <<= 1) tot += __shfl_xor(tot, m, 64);
    float inv = rsqrtf(tot / 2048.f);

    if (blockIdx.x >= 512) {
        int wv = threadIdx.x >> 6;
        int w = (blockIdx.x - 512) * 4 + wv;
        int b = w >> 9, o = w & 511;
        const float4* sr = (const float4*)(s_raw + b * 512);
        const float4* wr = (const float4*)(w2 + (size_t)o * 512);
        float acc = 0.f;
        #pragma unroll
        for (int q = 0; q < 2; q++) {
            float4 s = sr[lane * 2 + q], ww = wr[lane * 2 + q];
            float s0 = s.x * inv, s1 = s.y * inv, s2 = s.z * inv, s3 = s.w * inv;
            acc += ww.x * s0 * s0 + ww.y * s1 * s1 + ww.z * s2 * s2 + ww.w * s3 * s3;
        }
        #pragma unroll
        for (int m = 1; m < 64; m <<= 1) acc += __shfl_xor(acc, m, 64);
        if (lane == 0) dcoef[w] = rsqrtf(acc + 1e-8f);
    } else {
        // premod: pixel pairs. pair pp -> pixels (2pp, 2pp+1); r = pp/44, q = pp%44.
        int pb = blockIdx.x;
        int b = pb >> 7; int rem = pb & 127;
        int cg = rem >> 1, half = rem & 1;
        float sv[8];
        #pragma unroll
        for (int e = 0; e < 8; e++) sv[e] = s_raw[b * 512 + cg * 8 + e] * inv;
        const float* xbase = x + ((size_t)(b * 512 + cg * 8)) * (HW_ * HW_);
        unsigned short* op = xpad2 + ((size_t)(b * 64 + cg)) * XPIX * 8;
        int pr0 = half * (XPIX / 4), pr1 = pr0 + XPIX / 4;   // 1936 pairs per half
        for (int pr = pr0 + threadIdx.x; pr < pr1; pr += 256) {
            int r = pr / 44, q = pr - r * 44;
            uint4 d0, d1;
            if (r >= 2 && r < 86 && q >= 1 && q <= 42) {
                int off = (r - 2) * HW_ + 2 * q - 2;
                unsigned int w0[4], w1[4];
                #pragma unroll
                for (int e = 0; e < 4; e++) {
                    float2 fa = *(const float2*)(xbase + (size_t)(2 * e) * (HW_ * HW_) + off);
                    float2 fb = *(const float2*)(xbase + (size_t)(2 * e + 1) * (HW_ * HW_) + off);
                    w0[e] = (unsigned int)f2bf(fa.x * sv[2 * e]) | ((unsigned int)f2bf(fb.x * sv[2 * e + 1]) << 16);
                    w1[e] = (unsigned int)f2bf(fa.y * sv[2 * e]) | ((unsigned int)f2bf(fb.y * sv[2 * e + 1]) << 16);
                }
                d0.x = w0[0]; d0.y = w0[1]; d0.z = w0[2]; d0.w = w0[3];
                d1.x = w1[0]; d1.y = w1[1]; d1.z = w1[2]; d1.w = w1[3];
            } else {
                d0.x = d0.y = d0.z = d0.w = 0u;
                d1.x = d1.y = d1.z = d1.w = 0u;
            }
            *(uint4*)(op + (size_t)(2 * pr) * 8) = d0;
            *(uint4*)(op + (size_t)(2 * pr + 1) * 8) = d1;
        }
    }
}

// ---------- k_conv10: conv9 + setprio around MFMA clusters + staggered staging ----------
__global__ __launch_bounds__(256, 3) void k_conv10(const unsigned short* __restrict__ xpad2,
                                                   const unsigned short* __restrict__ wn3,
                                                   const float* __restrict__ dcoef,
                                                   const float* __restrict__ conv_b,
                                                   unsigned short* __restrict__ ypart) {
    __shared__ __align__(16) unsigned short xs[2][4][384][8];

    int bid = blockIdx.x;
    int wg = (bid & 7) * 264 + (bid >> 3);
    int tile = wg % 66; int rest = wg / 66;       // rest = b*8 + seg*4 + ot
    int ot = rest & 3; int seg = (rest >> 2) & 1; int b = rest >> 3;

    int tid = threadIdx.x;
    int wv = tid >> 6, lane = tid & 63;
    int kgrp = lane >> 4, ln15 = lane & 15;
    int tr = tile / 6, tc = tile % 6;
    int r0 = tr * 8; if (r0 > 78) r0 = 78;
    int c0p = tc * 16; if (c0p > 70) c0p = 70;
    int og = ot * 4 + wv;

    const unsigned short* xseg = xpad2 + ((size_t)(b * 64 + seg * 32 + wv)) * XPIX * 8;
    int pA = lane, pB = 64 + lane, pC = (128 + lane > 179) ? 179 : 128 + lane;
    const unsigned short* gA = xseg + ((size_t)((r0 + pA / 18) * XP_ + c0p + pA % 18)) * 8;
    const unsigned short* gB = xseg + ((size_t)((r0 + pB / 18) * XP_ + c0p + pB % 18)) * 8;
    const unsigned short* gC = xseg + ((size_t)((r0 + pC / 18) * XP_ + c0p + pC % 18)) * 8;
    const size_t cstride = (size_t)4 * XPIX * 8;

    const unsigned short* wb0 = wn3 + (size_t)(seg * 8) * 147456 + ((size_t)(og * 32 + ln15)) * 288 + kgrp * 8;
    const unsigned short* wb1 = wb0 + (size_t)16 * 288;

    f32x4 acc[8][2];
    #pragma unroll
    for (int g = 0; g < 8; g++) { acc[g][0] = (f32x4){0,0,0,0}; acc[g][1] = (f32x4){0,0,0,0}; }

    // prologue: stage chunks 0,1 into buf 0
    gload_lds16(gA,           &xs[0][wv][0][0]);
    gload_lds16(gB,           &xs[0][wv][64][0]);
    gload_lds16(gC,           &xs[0][wv][128][0]);
    gload_lds16(gA + cstride, &xs[0][wv][192][0]);
    gload_lds16(gB + cstride, &xs[0][wv][256][0]);
    gload_lds16(gC + cstride, &xs[0][wv][320][0]);
    gA += 2 * cstride; gB += 2 * cstride; gC += 2 * cstride;
    __syncthreads();

    #pragma unroll 1
    for (int ph = 0; ph < 4; ++ph) {
        int cur = ph & 1, nb = cur ^ 1;
        // stage even chunk of next pair, then compute half 0, stage odd chunk, compute half 1
        if (ph < 3) {
            gload_lds16(gA, &xs[nb][wv][0][0]);
            gload_lds16(gB, &xs[nb][wv][64][0]);
            gload_lds16(gC, &xs[nb][wv][128][0]);
        }
        #pragma unroll
        for (int hf = 0; hf < 2; ++hf) {
            int pbase = hf * 192;
            #pragma unroll
            for (int kw = 0; kw < 3; ++kw) {
                bf16x8 F[10];
                #pragma unroll
                for (int r = 0; r < 10; ++r)
                    F[r] = *(const bf16x8*)&xs[cur][kgrp][pbase + r * 18 + ln15 + kw][0];
                #pragma unroll
                for (int kh = 0; kh < 3; ++kh) {
                    int kk = kh * 3 + kw;
                    bf16x8 W0 = *(const bf16x8*)(wb0 + kk * 32);
                    bf16x8 W1 = *(const bf16x8*)(wb1 + kk * 32);
                    __builtin_amdgcn_s_setprio(1);
                    #pragma unroll
                    for (int g = 0; g < 8; ++g) {
                        acc[g][0] = __builtin_amdgcn_mfma_f32_16x16x32_bf16(W0, F[g + kh], acc[g][0], 0, 0, 0);
                        acc[g][1] = __builtin_amdgcn_mfma_f32_16x16x32_bf16(W1, F[g + kh], acc[g][1], 0, 0, 0);
                    }
                    __builtin_amdgcn_s_setprio(0);
                }
            }
            wb0 += 147456; wb1 += 147456;
            if (hf == 0 && ph < 3) {
                gload_lds16(gA + cstride, &xs[nb][wv][192][0]);
                gload_lds16(gB + cstride, &xs[nb][wv][256][0]);
                gload_lds16(gC + cstride, &xs[nb][wv][320][0]);
                gA += 2 * cstride; gB += 2 * cstride; gC += 2 * cstride;
            }
        }
        __syncthreads();
    }

    float dcv[2][4], bvs[2][4];
    #pragma unroll
    for (int nt = 0; nt < 2; nt++)
        #pragma unroll
        for (int r = 0; r < 4; r++) {
            int o = og * 32 + nt * 16 + kgrp * 4 + r;
            dcv[nt][r] = dcoef[b * 512 + o];
            bvs[nt][r] = seg ? conv_b[o] : 0.f;
        }
    unsigned short* yp = ypart + (size_t)seg * YSEG;
    int pcol = c0p + ln15;
    #pragma unroll
    for (int g = 0; g < 8; ++g) {
        int prow = r0 + g;
        #pragma unroll
        for (int nt = 0; nt < 2; nt++)
            #pragma unroll
            for (int r = 0; r < 4; r++) {
                int o = og * 32 + nt * 16 + kgrp * 4 + r;
                yp[((size_t)(b * 512 + o)) * NPIX + prow * HP_ + pcol] =
                    f2bf(acc[g][nt][r] * dcv[nt][r] + bvs[nt][r]);
            }
    }
}

// ---------- k_resample4: sliding-window register reuse in all filter stages ----------
__global__ __launch_bounds__(512) void k_resample4(const unsigned short* __restrict__ ypart,
                                                   float* __restrict__ out, Taps taps) {
    __shared__ __align__(16) char smem[23760 + 25344];
    float (*yt)[96]            = (float(*)[96])smem;            // [38][94 used]
    unsigned short (*upF)[180] = (unsigned short(*)[180])smem;  // [66][178 used]
    float (*upR)[96]           = (float(*)[96])(smem + 23760);  // [66][94 used]
    float (*dv)[180]           = (float(*)[180])(smem + 23760); // [28][178 used]

    int tid = threadIdx.x;
    int ts = blockIdx.x; int o = blockIdx.y; int b = blockIdx.z;
    int tr = ts * 28;
    const unsigned short* y0b = ypart + ((size_t)(b * 512 + o)) * NPIX;
    const unsigned short* y1b = y0b + YSEG;

    for (int idx = tid; idx < 38 * 94; idx += 512) {
        int rr = idx / 94, cc = idx % 94;
        int gr = tr - 4 + rr, gc = cc - 4;
        float v = 0.f;
        if (gr >= 0 && gr < HP_ && gc >= 0 && gc < HP_) {
            int p = gr * HP_ + gc;
            v = bf2f(y0b[p]) + bf2f(y1b[p]);
        }
        yt[rr][cc] = v;
    }
    __syncthreads();
    for (int idx = tid; idx < 11 * 94; idx += 512) {
        int ri = idx / 94, cc = idx % 94;
        int q0 = ri * 3;
        float w[8];
        #pragma unroll
        for (int u = 0; u < 8; u++) w[u] = yt[q0 + u][cc];
        #pragma unroll
        for (int j = 0; j < 3; j++) {
            float aE = 0.f, aO = 0.f;
            #pragma unroll
            for (int u = 0; u < 6; u++) {
                float v = w[j + u];
                aE += taps.fu[2 * u + 1] * v;
                aO += taps.fu[2 * u] * v;
            }
            upR[2 * (q0 + j)][cc] = aE;
            upR[2 * (q0 + j) + 1][cc] = aO;
        }
    }
    __syncthreads();
    for (int idx = tid; idx < 66 * 23; idx += 512) {
        int jr = idx / 23, rq = idx % 23;
        int q0 = rq * 4;
        int n = 89 - q0; if (n > 4) n = 4;
        float w[9];
        #pragma unroll
        for (int u = 0; u < 9; u++) w[u] = (u < n + 5) ? upR[jr][q0 + u] : 0.f;
        #pragma unroll
        for (int j = 0; j < 4; j++) {
            if (j < n) {
                float aE = 0.f, aO = 0.f;
                #pragma unroll
                for (int u = 0; u < 6; u++) {
                    float v = w[j + u];
                    aE += taps.fu[2 * u + 1] * v;
                    aO += taps.fu[2 * u] * v;
                }
                aE = (aE < 0.f ? aE * 0.2f : aE) * 1.4142135623730951f;
                aO = (aO < 0.f ? aO * 0.2f : aO) * 1.4142135623730951f;
                aE = fminf(fmaxf(aE, -256.f), 256.f);
                aO = fminf(fmaxf(aO, -256.f), 256.f);
                unsigned int pk = (unsigned int)f2bf(aE) | ((unsigned int)f2bf(aO) << 16);
                *(unsigned int*)&upF[jr][2 * (q0 + j)] = pk;
            }
        }
    }
    __syncthreads();
    for (int idx = tid; idx < 7 * 89; idx += 512) {
        int ri = idx / 89, jp = idx % 89;
        int ii0 = ri * 4;
        float lo[18], hi[18];
        #pragma unroll
        for (int t = 0; t < 18; t++) {
            unsigned int pk = *(const unsigned int*)&upF[2 * ii0 + t][2 * jp];
            lo[t] = bf2f((unsigned short)(pk & 0xffffu));
            hi[t] = bf2f((unsigned short)(pk >> 16));
        }
        #pragma unroll
        for (int j = 0; j < 4; j++) {
            float a0 = 0.f, a1 = 0.f;
            #pragma unroll
            for (int t = 0; t < 12; t++) {
                a0 += taps.fd[t] * lo[2 * j + t];
                a1 += taps.fd[t] * hi[2 * j + t];
            }
            *(float2*)&dv[ii0 + j][2 * jp] = make_float2(a0, a1);
        }
    }
    __syncthreads();
    for (int idx = tid; idx < 28 * 21; idx += 512) {
        int ii = idx / 21, rj = idx % 21;
        int jo0 = rj * 4;
        float w[18];
        const float2* dp = (const float2*)&dv[ii][2 * jo0];
        #pragma unroll
        for (int t = 0; t < 9; t++) {
            float2 d = dp[t];
            w[2 * t] = d.x; w[2 * t + 1] = d.y;
        }
        float4 res;
        #pragma unroll
        for (int j = 0; j < 4; j++) {
            float a = 0.f;
            #pragma unroll
            for (int t = 0; t < 12; t++) a += taps.fd[t] * w[2 * j + t];
            ((float*)&res)[j] = a;
        }
        *(float4*)&out[((size_t)(b * 512 + o) * 84 + (tr + ii)) * 84 + jo0] = res;
    }
}

// ---------- host: Kaiser lowpass design in double ----------
static double bessel_i0(double x) {
    double s = 1.0, t = 1.0;
    for (int k = 1; k < 60; k++) {
        double u = x / (2.0 * k);
        t *= u * u;
        s += t;
        if (t < 1e-18 * s) break;
    }
    return s;
}

static void design_taps(float* h12) {
    const int N = 12;
    const double cutoff = 16.0, width = 16.0, fs = 128.0;
    double nyq = 0.5 * fs;
    double atten = 2.285 * (N - 1) * M_PI * (width / nyq) + 7.95;
    double beta;
    if (atten > 50.0) beta = 0.1102 * (atten - 8.7);
    else if (atten > 21.0) beta = 0.5842 * pow(atten - 21.0, 0.4) + 0.07886 * (atten - 21.0);
    else beta = 0.0;
    double c = cutoff / nyq;
    double h[12]; double sum = 0.0;
    double ib = bessel_i0(beta);
    for (int n = 0; n < N; n++) {
        double m = n - (N - 1) / 2.0;
        double xx = c * m;
        double sinc = (xx == 0.0) ? 1.0 : sin(M_PI * xx) / (M_PI * xx);
        double t = 2.0 * n / (N - 1) - 1.0;
        double arg = 1.0 - t * t; if (arg < 0.0) arg = 0.0;
        double w = bessel_i0(beta * sqrt(arg)) / ib;
        h[n] = c * sinc * w;
        sum += h[n];
    }
    for (int n = 0; n < N; n++) h12[n] = (float)(h[n] / sum);
}

extern "C" void kernel_launch(void* const* d_in, const int* in_sizes, int n_in,
                              void* d_out, int out_size, void* d_ws, size_t ws_size,
                              hipStream_t stream) {
    const float* x      = (const float*)d_in[0];
    const float* wlat   = (const float*)d_in[1];
    const float* aff_w  = (const float*)d_in[2];
    const float* aff_b  = (const float*)d_in[3];
    const float* conv_w = (const float*)d_in[4];
    const float* conv_b = (const float*)d_in[5];
    float* out = (float*)d_out;

    // ws layout: (unused 8K) | dcoef 8K | w2 1M | wn3 4.5M | xpad2 31.7M | ypart 60.6M (~98 MiB)
    char* ws = (char*)d_ws;
    float* dcoef = (float*)ws + 2048;
    float* w2    = dcoef + 2048;
    unsigned short* wn3   = (unsigned short*)(w2 + 512 * 512);
    unsigned short* xpad2 = wn3 + (size_t)9 * 512 * 512;
    unsigned short* ypart = xpad2 + (size_t)B_ * 64 * XPIX * 8;
    // s_raw/parts alias ypart (consumed by k_moddc before k_conv10 writes)
    float* s_raw = (float*)ypart;
    float* parts = s_raw + 2048;

    Taps taps;
    float h[12];
    design_taps(h);
    for (int t = 0; t < 12; t++) {
        taps.fu[t] = 2.0f * h[11 - t];   // (FU*UP)[::-1]
        taps.fd[t] = h[11 - t];          // FD[::-1]
    }

    k_prep   <<<dim3(1024), dim3(256), 0, stream>>>(wlat, aff_w, aff_b, conv_w, s_raw, parts, wn3, w2);
    k_moddc  <<<dim3(1024), dim3(256), 0, stream>>>(s_raw, parts, w2, x, dcoef, xpad2);
    k_conv10 <<<dim3(2112), dim3(256), 0, stream>>>(xpad2, wn3, dcoef, conv_b, ypart);
    k_resample4<<<dim3(3, 512, 4), dim3(512), 0, stream>>>(ypart, out, taps);
}